// Round 1
// baseline (2200.917 us; speedup 1.0000x reference)
//
#include <hip/hip_runtime.h>
#include <math.h>

#define BT_TOK 32768
#define D_IN   1024
#define H1D    768
#define H2D    512
#define KCB    512

constexpr int BM = 128, BN = 128, BK = 16;
constexpr int LDT = BN + 4; // 132 floats, keeps float4 alignment (132 % 4 == 0)

// ---------------------------------------------------------------------------
// Tiled fp32 GEMM: C[M,N] = A[M,Kd] @ B + epilogue
// EPI: 0 = +bias, write; 1 = +bias, relu, write; 2 = VQ tile-argmin of
//      (cnorm[n] - 2*acc); 3 = recon: sum((acc+bias-x)^2) -> atomicAdd
// GATHER: A row m is codebook[gidx[m]]
// BTRANS: B is [N, Kd] row-major (we need B^T)
// ---------------------------------------------------------------------------
template<int EPI, bool GATHER, bool BTRANS>
__global__ __launch_bounds__(256, 2) void gemm_k(
    const float* __restrict__ A, const float* __restrict__ B,
    const float* __restrict__ bias, float* __restrict__ C,
    int M, int N, int Kd,
    const int* __restrict__ gidx,
    const float* __restrict__ extra,   // EPI2: cnorm[N]; EPI3: x[M,N]
    float* __restrict__ auxf,          // EPI2: cand_val; EPI3: atomic sum
    int* __restrict__ auxi,            // EPI2: cand_idx
    int ntiles)
{
    __shared__ float As[BK * LDT];
    __shared__ float Bs[BK * LDT];

    const int tid = threadIdx.x;
    const int tx = tid & 15, ty = tid >> 4;
    const int row0 = blockIdx.y * BM;
    const int col0 = blockIdx.x * BN;

    float acc[8][8];
#pragma unroll
    for (int i = 0; i < 8; ++i)
#pragma unroll
        for (int j = 0; j < 8; ++j) acc[i][j] = 0.f;

    const int lm = tid >> 2;        // 0..63
    const int lk = (tid & 3) * 4;   // 0,4,8,12

    int grow0 = 0, grow1 = 0;
    if (GATHER) {
        grow0 = gidx[row0 + lm];
        grow1 = gidx[row0 + lm + 64];
    }

    for (int k0 = 0; k0 < Kd; k0 += BK) {
        // --- stage A tile (As[k][m]) ---
        {
            const int ar0 = GATHER ? grow0 : (row0 + lm);
            const int ar1 = GATHER ? grow1 : (row0 + lm + 64);
            const float4 a0 = *(const float4*)(A + (size_t)ar0 * Kd + k0 + lk);
            const float4 a1 = *(const float4*)(A + (size_t)ar1 * Kd + k0 + lk);
            As[(lk + 0) * LDT + lm] = a0.x;
            As[(lk + 1) * LDT + lm] = a0.y;
            As[(lk + 2) * LDT + lm] = a0.z;
            As[(lk + 3) * LDT + lm] = a0.w;
            As[(lk + 0) * LDT + lm + 64] = a1.x;
            As[(lk + 1) * LDT + lm + 64] = a1.y;
            As[(lk + 2) * LDT + lm + 64] = a1.z;
            As[(lk + 3) * LDT + lm + 64] = a1.w;
        }
        // --- stage B tile (Bs[k][n]) ---
        if (BTRANS) {
            const float4 b0 = *(const float4*)(B + (size_t)(col0 + lm) * Kd + k0 + lk);
            const float4 b1 = *(const float4*)(B + (size_t)(col0 + lm + 64) * Kd + k0 + lk);
            Bs[(lk + 0) * LDT + lm] = b0.x;
            Bs[(lk + 1) * LDT + lm] = b0.y;
            Bs[(lk + 2) * LDT + lm] = b0.z;
            Bs[(lk + 3) * LDT + lm] = b0.w;
            Bs[(lk + 0) * LDT + lm + 64] = b1.x;
            Bs[(lk + 1) * LDT + lm + 64] = b1.y;
            Bs[(lk + 2) * LDT + lm + 64] = b1.z;
            Bs[(lk + 3) * LDT + lm + 64] = b1.w;
        } else {
            const int bk = tid >> 4;        // 0..15
            const int bn = (tid & 15) * 8;  // 0..120
            const float4 b0 = *(const float4*)(B + (size_t)(k0 + bk) * N + col0 + bn);
            const float4 b1 = *(const float4*)(B + (size_t)(k0 + bk) * N + col0 + bn + 4);
            *(float4*)&Bs[bk * LDT + bn] = b0;
            *(float4*)&Bs[bk * LDT + bn + 4] = b1;
        }
        __syncthreads();

#pragma unroll
        for (int kk = 0; kk < BK; ++kk) {
            const float4 a0 = *(const float4*)&As[kk * LDT + ty * 8];
            const float4 a1 = *(const float4*)&As[kk * LDT + ty * 8 + 4];
            const float4 b0 = *(const float4*)&Bs[kk * LDT + tx * 8];
            const float4 b1 = *(const float4*)&Bs[kk * LDT + tx * 8 + 4];
            const float av[8] = {a0.x, a0.y, a0.z, a0.w, a1.x, a1.y, a1.z, a1.w};
            const float bv[8] = {b0.x, b0.y, b0.z, b0.w, b1.x, b1.y, b1.z, b1.w};
#pragma unroll
            for (int i = 0; i < 8; ++i)
#pragma unroll
                for (int j = 0; j < 8; ++j)
                    acc[i][j] = fmaf(av[i], bv[j], acc[i][j]);
        }
        __syncthreads();
    }

    // ----------------- epilogues -----------------
    if (EPI == 0 || EPI == 1) {
        const float4 bb0 = *(const float4*)(bias + col0 + tx * 8);
        const float4 bb1 = *(const float4*)(bias + col0 + tx * 8 + 4);
        const float bv[8] = {bb0.x, bb0.y, bb0.z, bb0.w, bb1.x, bb1.y, bb1.z, bb1.w};
#pragma unroll
        for (int i = 0; i < 8; ++i) {
            const size_t row = row0 + ty * 8 + i;
            float o[8];
#pragma unroll
            for (int j = 0; j < 8; ++j) {
                o[j] = acc[i][j] + bv[j];
                if (EPI == 1) o[j] = fmaxf(o[j], 0.f);
            }
            float4* cp = (float4*)(C + row * N + col0 + tx * 8);
            cp[0] = make_float4(o[0], o[1], o[2], o[3]);
            cp[1] = make_float4(o[4], o[5], o[6], o[7]);
        }
    } else if (EPI == 2) {
        const float4 c0 = *(const float4*)(extra + col0 + tx * 8);
        const float4 c1 = *(const float4*)(extra + col0 + tx * 8 + 4);
        const float cn[8] = {c0.x, c0.y, c0.z, c0.w, c1.x, c1.y, c1.z, c1.w};
#pragma unroll
        for (int i = 0; i < 8; ++i) {
            float bestv = cn[0] - 2.f * acc[i][0];
            int besti = col0 + tx * 8;
#pragma unroll
            for (int j = 1; j < 8; ++j) {
                const float v = cn[j] - 2.f * acc[i][j];
                if (v < bestv) { bestv = v; besti = col0 + tx * 8 + j; }
            }
            // reduce across the 16 tx lanes (contiguous within the wave)
#pragma unroll
            for (int m = 1; m < 16; m <<= 1) {
                const float ov = __shfl_xor(bestv, m);
                const int oi = __shfl_xor(besti, m);
                if (ov < bestv || (ov == bestv && oi < besti)) { bestv = ov; besti = oi; }
            }
            if (tx == 0) {
                const size_t row = row0 + ty * 8 + i;
                auxf[row * ntiles + blockIdx.x] = bestv;
                auxi[row * ntiles + blockIdx.x] = besti;
            }
        }
    } else { // EPI == 3 : recon loss partial
        const float4 bb0 = *(const float4*)(bias + col0 + tx * 8);
        const float4 bb1 = *(const float4*)(bias + col0 + tx * 8 + 4);
        const float bv[8] = {bb0.x, bb0.y, bb0.z, bb0.w, bb1.x, bb1.y, bb1.z, bb1.w};
        float lsum = 0.f;
#pragma unroll
        for (int i = 0; i < 8; ++i) {
            const size_t row = row0 + ty * 8 + i;
            const float4 x0 = *(const float4*)(extra + row * N + col0 + tx * 8);
            const float4 x1 = *(const float4*)(extra + row * N + col0 + tx * 8 + 4);
            const float xv[8] = {x0.x, x0.y, x0.z, x0.w, x1.x, x1.y, x1.z, x1.w};
#pragma unroll
            for (int j = 0; j < 8; ++j) {
                const float d = acc[i][j] + bv[j] - xv[j];
                lsum = fmaf(d, d, lsum);
            }
        }
        __shared__ float red[256];
        red[tid] = lsum;
        __syncthreads();
        for (int s = 128; s > 0; s >>= 1) {
            if (tid < s) red[tid] += red[tid + s];
            __syncthreads();
        }
        if (tid == 0) atomicAdd(auxf, red[0]);
    }
}

// ---------------------------------------------------------------------------
// Wave-per-row LayerNorm + ReLU (in place). Optionally stash sum(out^2).
// ---------------------------------------------------------------------------
template<int H, bool ENORM>
__global__ __launch_bounds__(256) void ln_relu_k(
    float* __restrict__ buf, const float* __restrict__ g,
    const float* __restrict__ b, float* __restrict__ enorm)
{
    constexpr int E = H / 64;
    const int lane = threadIdx.x & 63;
    const int wid = threadIdx.x >> 6;
    const size_t row = (size_t)blockIdx.x * 4 + wid;
    float* p = buf + row * H;

    float h[E];
    float s = 0.f;
#pragma unroll
    for (int e = 0; e < E; ++e) { h[e] = p[lane + e * 64]; s += h[e]; }
#pragma unroll
    for (int m = 1; m < 64; m <<= 1) s += __shfl_xor(s, m);
    const float mu = s * (1.f / H);

    float vs = 0.f;
#pragma unroll
    for (int e = 0; e < E; ++e) { const float d = h[e] - mu; vs = fmaf(d, d, vs); }
#pragma unroll
    for (int m = 1; m < 64; m <<= 1) vs += __shfl_xor(vs, m);
    const float rstd = rsqrtf(vs * (1.f / H) + 1e-5f);

    float q = 0.f;
#pragma unroll
    for (int e = 0; e < E; ++e) {
        float o = (h[e] - mu) * rstd * g[lane + e * 64] + b[lane + e * 64];
        o = fmaxf(o, 0.f);
        p[lane + e * 64] = o;
        q = fmaf(o, o, q);
    }
    if (ENORM) {
#pragma unroll
        for (int m = 1; m < 64; m <<= 1) q += __shfl_xor(q, m);
        if (lane == 0) enorm[row] = q;
    }
}

// sum of squares per row of codebook [512 x 512]
__global__ __launch_bounds__(256) void rowsumsq_k(const float* __restrict__ A,
                                                  float* __restrict__ out)
{
    const int lane = threadIdx.x & 63;
    const int wid = threadIdx.x >> 6;
    const size_t row = (size_t)blockIdx.x * 4 + wid;
    const float* p = A + row * 512;
    float s = 0.f;
#pragma unroll
    for (int e = 0; e < 8; ++e) { const float v = p[lane + e * 64]; s = fmaf(v, v, s); }
#pragma unroll
    for (int m = 1; m < 64; m <<= 1) s += __shfl_xor(s, m);
    if (lane == 0) out[row] = s;
}

// reduce VQ tile candidates -> indices (float to d_out, int to ws), commit sum
__global__ __launch_bounds__(256) void vq_reduce_k(
    const float* __restrict__ cand_v, const int* __restrict__ cand_i,
    const float* __restrict__ enorm, float* __restrict__ out_idx_f,
    int* __restrict__ out_idx, float* __restrict__ commit_sum, int ntiles)
{
    const int tid = threadIdx.x;
    const int m = blockIdx.x * 256 + tid;
    float bv = cand_v[(size_t)m * ntiles];
    int bi = cand_i[(size_t)m * ntiles];
    for (int t = 1; t < ntiles; ++t) {
        const float v = cand_v[(size_t)m * ntiles + t];
        const int i = cand_i[(size_t)m * ntiles + t];
        if (v < bv) { bv = v; bi = i; }
    }
    out_idx_f[m] = (float)bi;
    out_idx[m] = bi;
    const float d2 = enorm[m] + bv;

    __shared__ float red[256];
    red[tid] = d2;
    __syncthreads();
    for (int s = 128; s > 0; s >>= 1) {
        if (tid < s) red[tid] += red[tid + s];
        __syncthreads();
    }
    if (tid == 0) atomicAdd(commit_sum, red[0]);
}

// pooled[b,:] = mean over T of codebook[idx[b,t],:]
__global__ __launch_bounds__(256) void pooled_k(const int* __restrict__ idx,
                                                const float* __restrict__ cb,
                                                float* __restrict__ pooled)
{
    const int b = blockIdx.x;
    const int d = threadIdx.x;
    float a0 = 0.f, a1 = 0.f;
    for (int t = 0; t < 512; ++t) {
        const int id = idx[b * 512 + t];
        a0 += cb[(size_t)id * 512 + d];
        a1 += cb[(size_t)id * 512 + d + 256];
    }
    pooled[b * 512 + d] = a0 * (1.f / 512.f);
    pooled[b * 512 + d + 256] = a1 * (1.f / 512.f);
}

// projection head + L2 normalize -> nproj [64 x 128]
__global__ __launch_bounds__(256) void proj_k(
    const float* __restrict__ pooled, const float* __restrict__ w1,
    const float* __restrict__ b1, const float* __restrict__ w2,
    const float* __restrict__ b2, float* __restrict__ nproj)
{
    __shared__ float sp[512];
    __shared__ float sh[256];
    __shared__ float red[128];
    const int b = blockIdx.x, tid = threadIdx.x;
    sp[tid] = pooled[b * 512 + tid];
    sp[tid + 256] = pooled[b * 512 + tid + 256];
    __syncthreads();

    float acc = b1[tid];
    for (int k = 0; k < 512; ++k) acc = fmaf(sp[k], w1[k * 256 + tid], acc);
    sh[tid] = fmaxf(acc, 0.f);
    __syncthreads();

    float p = 0.f;
    if (tid < 128) {
        p = b2[tid];
        for (int k = 0; k < 256; ++k) p = fmaf(sh[k], w2[k * 128 + tid], p);
        red[tid] = p * p;
    }
    __syncthreads();
    for (int s = 64; s > 0; s >>= 1) {
        if (tid < s) red[tid] += red[tid + s];
        __syncthreads();
    }
    if (tid < 128) {
        const float nrm = fmaxf(sqrtf(red[0]), 1e-12f);
        nproj[b * 128 + tid] = p / nrm;
    }
}

// similarity matrix + log-softmax diag + final loss combine
__global__ __launch_bounds__(256) void contrast_k(
    const float* __restrict__ nproj, const float* __restrict__ sums,
    float* __restrict__ out5)
{
    __shared__ float s_np[64 * 128];
    __shared__ float s_sim[64 * 64];
    __shared__ float s_row[64];
    const int tid = threadIdx.x;
    for (int i = tid; i < 64 * 128; i += 256) s_np[i] = nproj[i];
    __syncthreads();
    for (int p = tid; p < 64 * 64; p += 256) {
        const int i = p >> 6, j = p & 63;
        float d = 0.f;
        for (int k = 0; k < 128; ++k) d = fmaf(s_np[i * 128 + k], s_np[j * 128 + k], d);
        s_sim[p] = d * 10.f; // / TEMP
    }
    __syncthreads();
    if (tid < 64) {
        float mx = -1e30f;
        for (int j = 0; j < 64; ++j) mx = fmaxf(mx, s_sim[tid * 64 + j]);
        float se = 0.f;
        for (int j = 0; j < 64; ++j) se += expf(s_sim[tid * 64 + j] - mx);
        const float lse = mx + logf(se);
        s_row[tid] = s_sim[tid * 64 + tid] - lse;
    }
    __syncthreads();
    if (tid == 0) {
        float c = 0.f;
        for (int i = 0; i < 64; ++i) c += s_row[i];
        const float contr = -c / 64.f;
        const float recon = sums[0] / ((float)BT_TOK * (float)D_IN);
        const float commit = sums[1] / ((float)BT_TOK * (float)H2D);
        const float cbl = commit; // identical forward value
        const float total = recon * 1.0f + commit * 1.0f + cbl * 0.25f + contr * 0.5f;
        out5[0] = total;
        out5[1] = recon;
        out5[2] = commit;
        out5[3] = cbl;
        out5[4] = contr;
    }
}

__global__ void init_k(float* sums)
{
    if (threadIdx.x < 2) sums[threadIdx.x] = 0.f;
}

extern "C" void kernel_launch(void* const* d_in, const int* in_sizes, int n_in,
                              void* d_out, int out_size, void* d_ws, size_t ws_size,
                              hipStream_t stream)
{
    const float* x       = (const float*)d_in[0];
    const float* enc_w1  = (const float*)d_in[1];
    const float* enc_b1  = (const float*)d_in[2];
    const float* ln1_g   = (const float*)d_in[3];
    const float* ln1_b   = (const float*)d_in[4];
    const float* enc_w2  = (const float*)d_in[5];
    const float* enc_b2  = (const float*)d_in[6];
    const float* ln2_g   = (const float*)d_in[7];
    const float* ln2_b   = (const float*)d_in[8];
    const float* codebook= (const float*)d_in[9];
    const float* dec_w1  = (const float*)d_in[10];
    const float* dec_b1  = (const float*)d_in[11];
    const float* dec_w2  = (const float*)d_in[12];
    const float* dec_b2  = (const float*)d_in[13];
    const float* proj_w1 = (const float*)d_in[14];
    const float* proj_b1 = (const float*)d_in[15];
    const float* proj_w2 = (const float*)d_in[16];
    const float* proj_b2 = (const float*)d_in[17];
    float* out = (float*)d_out;

    float* ws = (float*)d_ws;
    size_t off = 0;
    float* h1     = ws + off; off += (size_t)BT_TOK * H1D;   // reused as dh later
    float* enc    = ws + off; off += (size_t)BT_TOK * H2D;
    float* cnorm  = ws + off; off += KCB;
    float* enorm  = ws + off; off += BT_TOK;
    float* cand_v = ws + off; off += (size_t)BT_TOK * 4;
    int*   cand_i = (int*)(ws + off); off += (size_t)BT_TOK * 4;
    int*   idxbuf = (int*)(ws + off); off += BT_TOK;
    float* pooled = ws + off; off += 64 * 512;
    float* nproj  = ws + off; off += 64 * 128;
    float* sums   = ws + off; off += 2; // [recon_sum, commit_sum]

    const dim3 blk(256);
    const int NT_VQ = KCB / BN; // 4

    hipLaunchKernelGGL(init_k, dim3(1), blk, 0, stream, sums);

    // encoder layer 1: h1 = x @ enc_w1 + b1
    gemm_k<0, false, false><<<dim3(H1D / BN, BT_TOK / BM), blk, 0, stream>>>(
        x, enc_w1, enc_b1, h1, BT_TOK, H1D, D_IN, nullptr, nullptr, nullptr, nullptr, 0);
    ln_relu_k<H1D, false><<<dim3(BT_TOK / 4), blk, 0, stream>>>(h1, ln1_g, ln1_b, nullptr);

    // encoder layer 2: enc = h1 @ enc_w2 + b2
    gemm_k<0, false, false><<<dim3(H2D / BN, BT_TOK / BM), blk, 0, stream>>>(
        h1, enc_w2, enc_b2, enc, BT_TOK, H2D, H1D, nullptr, nullptr, nullptr, nullptr, 0);
    ln_relu_k<H2D, true><<<dim3(BT_TOK / 4), blk, 0, stream>>>(enc, ln2_g, ln2_b, enorm);

    // VQ
    rowsumsq_k<<<dim3(KCB / 4), blk, 0, stream>>>(codebook, cnorm);
    gemm_k<2, false, true><<<dim3(KCB / BN, BT_TOK / BM), blk, 0, stream>>>(
        enc, codebook, nullptr, nullptr, BT_TOK, KCB, H2D, nullptr, cnorm, cand_v, cand_i, NT_VQ);
    vq_reduce_k<<<dim3(BT_TOK / 256), blk, 0, stream>>>(
        cand_v, cand_i, enorm, out, idxbuf, sums + 1, NT_VQ);

    pooled_k<<<dim3(64), blk, 0, stream>>>(idxbuf, codebook, pooled);

    // decoder layer 1 (gathered A = codebook[idx]): dh = relu(Q @ dec_w1 + b) -> h1 buf
    gemm_k<1, true, false><<<dim3(H1D / BN, BT_TOK / BM), blk, 0, stream>>>(
        codebook, dec_w1, dec_b1, h1, BT_TOK, H1D, H2D, idxbuf, nullptr, nullptr, nullptr, 0);

    // decoder layer 2 + fused recon loss (decoded never materialized)
    gemm_k<3, false, false><<<dim3(D_IN / BN, BT_TOK / BM), blk, 0, stream>>>(
        h1, dec_w2, dec_b2, nullptr, BT_TOK, D_IN, H1D, nullptr, x, sums, nullptr, 0);

    // projection head + contrastive + final losses
    proj_k<<<dim3(64), blk, 0, stream>>>(pooled, proj_w1, proj_b1, proj_w2, proj_b2, nproj);
    contrast_k<<<dim3(1), blk, 0, stream>>>(nproj, sums, out + BT_TOK);
}

// Round 2
// 1609.559 us; speedup vs baseline: 1.3674x; 1.3674x over previous
//
#include <hip/hip_runtime.h>
#include <math.h>

#define BT_TOK 32768
#define D_IN   1024
#define H1D    768
#define H2D    512
#define KCB    512

constexpr int BM = 128, BN = 128, BK = 16;
constexpr int LDT = BN + 4;

typedef short bf16x8 __attribute__((ext_vector_type(8)));
typedef float f32x4 __attribute__((ext_vector_type(4)));

#define GLDS16(g, l) \
    __builtin_amdgcn_global_load_lds((const __attribute__((address_space(1))) void*)(g), \
                                     (__attribute__((address_space(3))) void*)(l), 16, 0, 0)

__device__ __forceinline__ unsigned short f2bf(float f) {
    union { float f; unsigned u; } v; v.f = f;
    const unsigned r = v.u + 0x7FFFu + ((v.u >> 16) & 1u);
    return (unsigned short)(r >> 16);
}

// ---------------------------------------------------------------------------
// fp32 tiled GEMM (encoder + VQ path; argmin must stay fp32-exact).
// Microtile remapped to 4+4 split rows/cols to kill LDS bank conflicts.
// EPI: 0 = +bias write; 1 = +bias relu write; 2 = VQ tile-argmin; 3 = recon
// ---------------------------------------------------------------------------
template<int EPI, bool BTRANS>
__global__ __launch_bounds__(256, 2) void gemm_k(
    const float* __restrict__ A, const float* __restrict__ B,
    const float* __restrict__ bias, float* __restrict__ C,
    int M, int N, int Kd,
    const float* __restrict__ extra,   // EPI2: cnorm[N]; EPI3: x[M,N]
    float* __restrict__ auxf,          // EPI2: cand_val; EPI3: atomic sum
    int* __restrict__ auxi,            // EPI2: cand_idx
    int ntiles)
{
    __shared__ float As[BK * LDT];
    __shared__ float Bs[BK * LDT];

    const int tid = threadIdx.x;
    const int tx = tid & 15, ty = tid >> 4;
    const int row0 = blockIdx.y * BM;
    const int col0 = blockIdx.x * BN;

    float acc[8][8];
#pragma unroll
    for (int i = 0; i < 8; ++i)
#pragma unroll
        for (int j = 0; j < 8; ++j) acc[i][j] = 0.f;

    const int lm = tid >> 2;        // 0..63
    const int lk = (tid & 3) * 4;   // 0,4,8,12

    for (int k0 = 0; k0 < Kd; k0 += BK) {
        // --- stage A tile (As[k][m]) ---
        {
            const float4 a0 = *(const float4*)(A + (size_t)(row0 + lm) * Kd + k0 + lk);
            const float4 a1 = *(const float4*)(A + (size_t)(row0 + lm + 64) * Kd + k0 + lk);
            As[(lk + 0) * LDT + lm] = a0.x;
            As[(lk + 1) * LDT + lm] = a0.y;
            As[(lk + 2) * LDT + lm] = a0.z;
            As[(lk + 3) * LDT + lm] = a0.w;
            As[(lk + 0) * LDT + lm + 64] = a1.x;
            As[(lk + 1) * LDT + lm + 64] = a1.y;
            As[(lk + 2) * LDT + lm + 64] = a1.z;
            As[(lk + 3) * LDT + lm + 64] = a1.w;
        }
        // --- stage B tile (Bs[k][n]) ---
        if (BTRANS) {
            const float4 b0 = *(const float4*)(B + (size_t)(col0 + lm) * Kd + k0 + lk);
            const float4 b1 = *(const float4*)(B + (size_t)(col0 + lm + 64) * Kd + k0 + lk);
            Bs[(lk + 0) * LDT + lm] = b0.x;
            Bs[(lk + 1) * LDT + lm] = b0.y;
            Bs[(lk + 2) * LDT + lm] = b0.z;
            Bs[(lk + 3) * LDT + lm] = b0.w;
            Bs[(lk + 0) * LDT + lm + 64] = b1.x;
            Bs[(lk + 1) * LDT + lm + 64] = b1.y;
            Bs[(lk + 2) * LDT + lm + 64] = b1.z;
            Bs[(lk + 3) * LDT + lm + 64] = b1.w;
        } else {
            const int bk = tid >> 4;        // 0..15
            const int bn = (tid & 15) * 4;  // 4+4 split: conflict-free stores
            const float4 b0 = *(const float4*)(B + (size_t)(k0 + bk) * N + col0 + bn);
            const float4 b1 = *(const float4*)(B + (size_t)(k0 + bk) * N + col0 + bn + 64);
            *(float4*)&Bs[bk * LDT + bn] = b0;
            *(float4*)&Bs[bk * LDT + bn + 64] = b1;
        }
        __syncthreads();

#pragma unroll
        for (int kk = 0; kk < BK; ++kk) {
            // 4+4 split fragments: lane stride 4 floats -> 2-way bank alias (free)
            const float4 a0 = *(const float4*)&As[kk * LDT + ty * 4];
            const float4 a1 = *(const float4*)&As[kk * LDT + 64 + ty * 4];
            const float4 b0 = *(const float4*)&Bs[kk * LDT + tx * 4];
            const float4 b1 = *(const float4*)&Bs[kk * LDT + 64 + tx * 4];
            const float av[8] = {a0.x, a0.y, a0.z, a0.w, a1.x, a1.y, a1.z, a1.w};
            const float bv[8] = {b0.x, b0.y, b0.z, b0.w, b1.x, b1.y, b1.z, b1.w};
#pragma unroll
            for (int i = 0; i < 8; ++i)
#pragma unroll
                for (int j = 0; j < 8; ++j)
                    acc[i][j] = fmaf(av[i], bv[j], acc[i][j]);
        }
        __syncthreads();
    }

    // row/col mapping for the 4+4 split microtile
    // row(i) = row0 + (i<4 ? ty*4+i : 64+ty*4+i-4), col(j) likewise with tx
    if (EPI == 0 || EPI == 1) {
        const float4 bb0 = *(const float4*)(bias + col0 + tx * 4);
        const float4 bb1 = *(const float4*)(bias + col0 + 64 + tx * 4);
        const float bv[8] = {bb0.x, bb0.y, bb0.z, bb0.w, bb1.x, bb1.y, bb1.z, bb1.w};
#pragma unroll
        for (int i = 0; i < 8; ++i) {
            const size_t row = row0 + ((i < 4) ? (ty * 4 + i) : (64 + ty * 4 + i - 4));
            float o[8];
#pragma unroll
            for (int j = 0; j < 8; ++j) {
                o[j] = acc[i][j] + bv[j];
                if (EPI == 1) o[j] = fmaxf(o[j], 0.f);
            }
            *(float4*)(C + row * N + col0 + tx * 4) = make_float4(o[0], o[1], o[2], o[3]);
            *(float4*)(C + row * N + col0 + 64 + tx * 4) = make_float4(o[4], o[5], o[6], o[7]);
        }
    } else if (EPI == 2) {
        const float4 c0 = *(const float4*)(extra + col0 + tx * 4);
        const float4 c1 = *(const float4*)(extra + col0 + 64 + tx * 4);
        const float cn[8] = {c0.x, c0.y, c0.z, c0.w, c1.x, c1.y, c1.z, c1.w};
#pragma unroll
        for (int i = 0; i < 8; ++i) {
            float bestv = cn[0] - 2.f * acc[i][0];
            int besti = col0 + tx * 4;
#pragma unroll
            for (int j = 1; j < 8; ++j) {
                const float v = cn[j] - 2.f * acc[i][j];
                const int cj = col0 + ((j < 4) ? (tx * 4 + j) : (64 + tx * 4 + j - 4));
                if (v < bestv) { bestv = v; besti = cj; }
            }
#pragma unroll
            for (int m = 1; m < 16; m <<= 1) {
                const float ov = __shfl_xor(bestv, m);
                const int oi = __shfl_xor(besti, m);
                if (ov < bestv || (ov == bestv && oi < besti)) { bestv = ov; besti = oi; }
            }
            if (tx == 0) {
                const size_t row = row0 + ((i < 4) ? (ty * 4 + i) : (64 + ty * 4 + i - 4));
                auxf[row * ntiles + blockIdx.x] = bestv;
                auxi[row * ntiles + blockIdx.x] = besti;
            }
        }
    } else { // EPI == 3 : recon loss partial (fp32 fallback; unused now but kept)
        const float4 bb0 = *(const float4*)(bias + col0 + tx * 4);
        const float4 bb1 = *(const float4*)(bias + col0 + 64 + tx * 4);
        const float bv[8] = {bb0.x, bb0.y, bb0.z, bb0.w, bb1.x, bb1.y, bb1.z, bb1.w};
        float lsum = 0.f;
#pragma unroll
        for (int i = 0; i < 8; ++i) {
            const size_t row = row0 + ((i < 4) ? (ty * 4 + i) : (64 + ty * 4 + i - 4));
            const float4 x0 = *(const float4*)(extra + row * N + col0 + tx * 4);
            const float4 x1 = *(const float4*)(extra + row * N + col0 + 64 + tx * 4);
            const float xv[8] = {x0.x, x0.y, x0.z, x0.w, x1.x, x1.y, x1.z, x1.w};
#pragma unroll
            for (int j = 0; j < 8; ++j) {
                const float d = acc[i][j] + bv[j] - xv[j];
                lsum = fmaf(d, d, lsum);
            }
        }
        __shared__ float red[256];
        red[tid] = lsum;
        __syncthreads();
        for (int s = 128; s > 0; s >>= 1) {
            if (tid < s) red[tid] += red[tid + s];
            __syncthreads();
        }
        if (tid == 0) atomicAdd(auxf, red[0]);
    }
}

// ---------------------------------------------------------------------------
// bf16 MFMA GEMM (m97 structure): 128x128 tile, 16x16x32 bf16, BK=32,
// global_load_lds width=16. A is [M][Kd] bf16 (optionally row-gathered),
// BT is [N][Kd] bf16. EPI 0: bias+relu -> bf16 C. EPI 1: recon-loss reduce.
// ---------------------------------------------------------------------------
template<int EPI>
__global__ __launch_bounds__(256) void mfma_gemm_k(
    const unsigned short* __restrict__ A, const unsigned short* __restrict__ BT,
    const float* __restrict__ bias, unsigned short* __restrict__ Cbf,
    const float* __restrict__ Xref, float* __restrict__ lsum_out,
    const int* __restrict__ gidx, int N, int Kd)
{
    __shared__ __align__(16) unsigned short sA[128 * 32];
    __shared__ __align__(16) unsigned short sB[128 * 32];

    const int t = threadIdx.x;
    const int lane = t & 63, wave = t >> 6;
    const int wm = wave & 1, wn = wave >> 1;
    const int row0 = blockIdx.y * 128, col0 = blockIdx.x * 128;

    f32x4 acc[4][4];
#pragma unroll
    for (int i = 0; i < 4; ++i)
#pragma unroll
        for (int j = 0; j < 4; ++j) acc[i][j] = (f32x4){0.f, 0.f, 0.f, 0.f};

    const int sr = t >> 2;          // 0..63 staging row (within half)
    const int sk = (t & 3) * 8;     // bf16 offset within row

    int ar0 = row0 + sr, ar1 = row0 + 64 + sr;
    if (gidx) { ar0 = gidx[row0 + sr]; ar1 = gidx[row0 + 64 + sr]; }
    const unsigned short* gA0 = A + (size_t)ar0 * Kd + sk;
    const unsigned short* gA1 = A + (size_t)ar1 * Kd + sk;
    const unsigned short* gB0 = BT + (size_t)(col0 + sr) * Kd + sk;
    const unsigned short* gB1 = BT + (size_t)(col0 + 64 + sr) * Kd + sk;

    char* sAc = (char*)sA;
    char* sBc = (char*)sB;
    // wave-uniform LDS bases; lane deposits at base + lane*16
    char* dA0 = sAc + wave * 1024;
    char* dA1 = sAc + 4096 + wave * 1024;
    char* dB0 = sBc + wave * 1024;
    char* dB1 = sBc + 4096 + wave * 1024;

    const int fr = lane & 15;             // row within 16-tile
    const int fk = (lane >> 4) * 16;      // byte offset of the 8-bf16 k-chunk

    for (int k0 = 0; k0 < Kd; k0 += 32) {
        GLDS16(gA0 + k0, dA0);
        GLDS16(gA1 + k0, dA1);
        GLDS16(gB0 + k0, dB0);
        GLDS16(gB1 + k0, dB1);
        __syncthreads();

        bf16x8 a[4], b[4];
#pragma unroll
        for (int mi = 0; mi < 4; ++mi)
            a[mi] = *(const bf16x8*)(sAc + (size_t)(wm * 64 + mi * 16 + fr) * 64 + fk);
#pragma unroll
        for (int ni = 0; ni < 4; ++ni)
            b[ni] = *(const bf16x8*)(sBc + (size_t)(wn * 64 + ni * 16 + fr) * 64 + fk);
#pragma unroll
        for (int mi = 0; mi < 4; ++mi)
#pragma unroll
            for (int ni = 0; ni < 4; ++ni)
                acc[mi][ni] = __builtin_amdgcn_mfma_f32_16x16x32_bf16(
                    a[mi], b[ni], acc[mi][ni], 0, 0, 0);
        __syncthreads();
    }

    const int cR = (lane >> 4) * 4;   // C/D row base: row = quad*4 + reg  [m89]
    const int cC = lane & 15;         // C/D col = lane & 15

    if (EPI == 0) {
#pragma unroll
        for (int ni = 0; ni < 4; ++ni) {
            const int col = col0 + wn * 64 + ni * 16 + cC;
            const float bb = bias[col];
#pragma unroll
            for (int mi = 0; mi < 4; ++mi)
#pragma unroll
                for (int r = 0; r < 4; ++r) {
                    const size_t row = row0 + wm * 64 + mi * 16 + cR + r;
                    const float v = fmaxf(acc[mi][ni][r] + bb, 0.f);
                    Cbf[row * N + col] = f2bf(v);
                }
        }
    } else {
        float ls = 0.f;
#pragma unroll
        for (int ni = 0; ni < 4; ++ni) {
            const int col = col0 + wn * 64 + ni * 16 + cC;
            const float bb = bias[col];
#pragma unroll
            for (int mi = 0; mi < 4; ++mi)
#pragma unroll
                for (int r = 0; r < 4; ++r) {
                    const size_t row = row0 + wm * 64 + mi * 16 + cR + r;
                    const float d = acc[mi][ni][r] + bb - Xref[row * N + col];
                    ls = fmaf(d, d, ls);
                }
        }
        __shared__ float red[256];
        red[t] = ls;
        __syncthreads();
        for (int s = 128; s > 0; s >>= 1) {
            if (t < s) red[t] += red[t + s];
            __syncthreads();
        }
        if (t == 0) atomicAdd(lsum_out, red[0]);
    }
}

// dst[N][K] bf16 = transpose(src[K][N] fp32)
__global__ __launch_bounds__(256) void convT_k(const float* __restrict__ src,
                                               unsigned short* __restrict__ dst,
                                               int K, int N)
{
    const int i = blockIdx.x * 256 + threadIdx.x;
    if (i < K * N) {
        const int n = i / K, k = i % K;
        dst[i] = f2bf(src[(size_t)k * N + n]);
    }
}

__global__ __launch_bounds__(256) void conv_k(const float* __restrict__ src,
                                              unsigned short* __restrict__ dst, int n)
{
    const int i = blockIdx.x * 256 + threadIdx.x;
    if (i < n) dst[i] = f2bf(src[i]);
}

// ---------------------------------------------------------------------------
template<int H, bool ENORM>
__global__ __launch_bounds__(256) void ln_relu_k(
    float* __restrict__ buf, const float* __restrict__ g,
    const float* __restrict__ b, float* __restrict__ enorm)
{
    constexpr int E = H / 64;
    const int lane = threadIdx.x & 63;
    const int wid = threadIdx.x >> 6;
    const size_t row = (size_t)blockIdx.x * 4 + wid;
    float* p = buf + row * H;

    float h[E];
    float s = 0.f;
#pragma unroll
    for (int e = 0; e < E; ++e) { h[e] = p[lane + e * 64]; s += h[e]; }
#pragma unroll
    for (int m = 1; m < 64; m <<= 1) s += __shfl_xor(s, m);
    const float mu = s * (1.f / H);

    float vs = 0.f;
#pragma unroll
    for (int e = 0; e < E; ++e) { const float d = h[e] - mu; vs = fmaf(d, d, vs); }
#pragma unroll
    for (int m = 1; m < 64; m <<= 1) vs += __shfl_xor(vs, m);
    const float rstd = rsqrtf(vs * (1.f / H) + 1e-5f);

    float q = 0.f;
#pragma unroll
    for (int e = 0; e < E; ++e) {
        float o = (h[e] - mu) * rstd * g[lane + e * 64] + b[lane + e * 64];
        o = fmaxf(o, 0.f);
        p[lane + e * 64] = o;
        q = fmaf(o, o, q);
    }
    if (ENORM) {
#pragma unroll
        for (int m = 1; m < 64; m <<= 1) q += __shfl_xor(q, m);
        if (lane == 0) enorm[row] = q;
    }
}

__global__ __launch_bounds__(256) void rowsumsq_k(const float* __restrict__ A,
                                                  float* __restrict__ out)
{
    const int lane = threadIdx.x & 63;
    const int wid = threadIdx.x >> 6;
    const size_t row = (size_t)blockIdx.x * 4 + wid;
    const float* p = A + row * 512;
    float s = 0.f;
#pragma unroll
    for (int e = 0; e < 8; ++e) { const float v = p[lane + e * 64]; s = fmaf(v, v, s); }
#pragma unroll
    for (int m = 1; m < 64; m <<= 1) s += __shfl_xor(s, m);
    if (lane == 0) out[row] = s;
}

__global__ __launch_bounds__(256) void vq_reduce_k(
    const float* __restrict__ cand_v, const int* __restrict__ cand_i,
    const float* __restrict__ enorm, float* __restrict__ out_idx_f,
    int* __restrict__ out_idx, float* __restrict__ commit_sum, int ntiles)
{
    const int tid = threadIdx.x;
    const int m = blockIdx.x * 256 + tid;
    float bv = cand_v[(size_t)m * ntiles];
    int bi = cand_i[(size_t)m * ntiles];
    for (int t = 1; t < ntiles; ++t) {
        const float v = cand_v[(size_t)m * ntiles + t];
        const int i = cand_i[(size_t)m * ntiles + t];
        if (v < bv) { bv = v; bi = i; }
    }
    out_idx_f[m] = (float)bi;
    out_idx[m] = bi;
    const float d2 = enorm[m] + bv;

    __shared__ float red[256];
    red[tid] = d2;
    __syncthreads();
    for (int s = 128; s > 0; s >>= 1) {
        if (tid < s) red[tid] += red[tid + s];
        __syncthreads();
    }
    if (tid == 0) atomicAdd(commit_sum, red[0]);
}

__global__ __launch_bounds__(256) void pooled_k(const int* __restrict__ idx,
                                                const float* __restrict__ cb,
                                                float* __restrict__ pooled)
{
    const int b = blockIdx.x;
    const int d = threadIdx.x;
    float a0 = 0.f, a1 = 0.f;
    for (int t = 0; t < 512; ++t) {
        const int id = idx[b * 512 + t];
        a0 += cb[(size_t)id * 512 + d];
        a1 += cb[(size_t)id * 512 + d + 256];
    }
    pooled[b * 512 + d] = a0 * (1.f / 512.f);
    pooled[b * 512 + d + 256] = a1 * (1.f / 512.f);
}

__global__ __launch_bounds__(256) void proj_k(
    const float* __restrict__ pooled, const float* __restrict__ w1,
    const float* __restrict__ b1, const float* __restrict__ w2,
    const float* __restrict__ b2, float* __restrict__ nproj)
{
    __shared__ float sp[512];
    __shared__ float sh[256];
    __shared__ float red[128];
    const int b = blockIdx.x, tid = threadIdx.x;
    sp[tid] = pooled[b * 512 + tid];
    sp[tid + 256] = pooled[b * 512 + tid + 256];
    __syncthreads();

    float acc = b1[tid];
    for (int k = 0; k < 512; ++k) acc = fmaf(sp[k], w1[k * 256 + tid], acc);
    sh[tid] = fmaxf(acc, 0.f);
    __syncthreads();

    float p = 0.f;
    if (tid < 128) {
        p = b2[tid];
        for (int k = 0; k < 256; ++k) p = fmaf(sh[k], w2[k * 128 + tid], p);
        red[tid] = p * p;
    }
    __syncthreads();
    for (int s = 64; s > 0; s >>= 1) {
        if (tid < s) red[tid] += red[tid + s];
        __syncthreads();
    }
    if (tid < 128) {
        const float nrm = fmaxf(sqrtf(red[0]), 1e-12f);
        nproj[b * 128 + tid] = p / nrm;
    }
}

__global__ __launch_bounds__(256) void contrast_k(
    const float* __restrict__ nproj, const float* __restrict__ sums,
    float* __restrict__ out5)
{
    __shared__ float s_np[64 * 128];
    __shared__ float s_sim[64 * 64];
    __shared__ float s_row[64];
    const int tid = threadIdx.x;
    for (int i = tid; i < 64 * 128; i += 256) s_np[i] = nproj[i];
    __syncthreads();
    for (int p = tid; p < 64 * 64; p += 256) {
        const int i = p >> 6, j = p & 63;
        float d = 0.f;
        for (int k = 0; k < 128; ++k) d = fmaf(s_np[i * 128 + k], s_np[j * 128 + k], d);
        s_sim[p] = d * 10.f;
    }
    __syncthreads();
    if (tid < 64) {
        float mx = -1e30f;
        for (int j = 0; j < 64; ++j) mx = fmaxf(mx, s_sim[tid * 64 + j]);
        float se = 0.f;
        for (int j = 0; j < 64; ++j) se += expf(s_sim[tid * 64 + j] - mx);
        const float lse = mx + logf(se);
        s_row[tid] = s_sim[tid * 64 + tid] - lse;
    }
    __syncthreads();
    if (tid == 0) {
        float c = 0.f;
        for (int i = 0; i < 64; ++i) c += s_row[i];
        const float contr = -c / 64.f;
        const float recon = sums[0] / ((float)BT_TOK * (float)D_IN);
        const float commit = sums[1] / ((float)BT_TOK * (float)H2D);
        const float cbl = commit;
        const float total = recon * 1.0f + commit * 1.0f + cbl * 0.25f + contr * 0.5f;
        out5[0] = total;
        out5[1] = recon;
        out5[2] = commit;
        out5[3] = cbl;
        out5[4] = contr;
    }
}

__global__ void init_k(float* sums)
{
    if (threadIdx.x < 2) sums[threadIdx.x] = 0.f;
}

extern "C" void kernel_launch(void* const* d_in, const int* in_sizes, int n_in,
                              void* d_out, int out_size, void* d_ws, size_t ws_size,
                              hipStream_t stream)
{
    const float* x       = (const float*)d_in[0];
    const float* enc_w1  = (const float*)d_in[1];
    const float* enc_b1  = (const float*)d_in[2];
    const float* ln1_g   = (const float*)d_in[3];
    const float* ln1_b   = (const float*)d_in[4];
    const float* enc_w2  = (const float*)d_in[5];
    const float* enc_b2  = (const float*)d_in[6];
    const float* ln2_g   = (const float*)d_in[7];
    const float* ln2_b   = (const float*)d_in[8];
    const float* codebook= (const float*)d_in[9];
    const float* dec_w1  = (const float*)d_in[10];
    const float* dec_b1  = (const float*)d_in[11];
    const float* dec_w2  = (const float*)d_in[12];
    const float* dec_b2  = (const float*)d_in[13];
    const float* proj_w1 = (const float*)d_in[14];
    const float* proj_b1 = (const float*)d_in[15];
    const float* proj_w2 = (const float*)d_in[16];
    const float* proj_b2 = (const float*)d_in[17];
    float* out = (float*)d_out;

    float* ws = (float*)d_ws;
    size_t off = 0;
    float* h1     = ws + off; off += (size_t)BT_TOK * H1D;   // fp32 encoder hidden
    float* enc    = ws + off; off += (size_t)BT_TOK * H2D;   // fp32 encoded; later aliased by dh_bf16
    float* cnorm  = ws + off; off += KCB;
    float* enorm  = ws + off; off += BT_TOK;
    float* cand_v = ws + off; off += (size_t)BT_TOK * 4;
    int*   cand_i = (int*)(ws + off); off += (size_t)BT_TOK * 4;
    int*   idxbuf = (int*)(ws + off); off += BT_TOK;
    float* pooled = ws + off; off += 64 * 512;
    float* nproj  = ws + off; off += 64 * 128;
    float* sums   = ws + off; off += 2;
    unsigned short* cb_bf = (unsigned short*)(ws + off); off += (KCB * H2D) / 2;
    unsigned short* w1T   = (unsigned short*)(ws + off); off += (H1D * H2D) / 2;  // [768][512]
    unsigned short* w2T   = (unsigned short*)(ws + off); off += (D_IN * H1D) / 2; // [1024][768]
    // dh bf16 [32768][768] aliases enc (48MB <= 64MB); enc dead after VQ gemm
    unsigned short* dh_bf = (unsigned short*)enc;

    const dim3 blk(256);
    const int NT_VQ = KCB / BN; // 4

    hipLaunchKernelGGL(init_k, dim3(1), blk, 0, stream, sums);

    // weight/codebook bf16 conversions (tiny)
    conv_k<<<dim3((KCB * H2D + 255) / 256), blk, 0, stream>>>(codebook, cb_bf, KCB * H2D);
    convT_k<<<dim3((H2D * H1D + 255) / 256), blk, 0, stream>>>(dec_w1, w1T, H2D, H1D);
    convT_k<<<dim3((H1D * D_IN + 255) / 256), blk, 0, stream>>>(dec_w2, w2T, H1D, D_IN);

    // encoder layer 1: h1 = x @ enc_w1 + b1 ; LN+ReLU
    gemm_k<0, false><<<dim3(H1D / BN, BT_TOK / BM), blk, 0, stream>>>(
        x, enc_w1, enc_b1, h1, BT_TOK, H1D, D_IN, nullptr, nullptr, nullptr, 0);
    ln_relu_k<H1D, false><<<dim3(BT_TOK / 4), blk, 0, stream>>>(h1, ln1_g, ln1_b, nullptr);

    // encoder layer 2: enc = h1 @ enc_w2 + b2 ; LN+ReLU (+enorm)
    gemm_k<0, false><<<dim3(H2D / BN, BT_TOK / BM), blk, 0, stream>>>(
        h1, enc_w2, enc_b2, enc, BT_TOK, H2D, H1D, nullptr, nullptr, nullptr, 0);
    ln_relu_k<H2D, true><<<dim3(BT_TOK / 4), blk, 0, stream>>>(enc, ln2_g, ln2_b, enorm);

    // VQ (fp32-exact argmin)
    rowsumsq_k<<<dim3(KCB / 4), blk, 0, stream>>>(codebook, cnorm);
    gemm_k<2, true><<<dim3(KCB / BN, BT_TOK / BM), blk, 0, stream>>>(
        enc, codebook, nullptr, nullptr, BT_TOK, KCB, H2D, cnorm, cand_v, cand_i, NT_VQ);
    vq_reduce_k<<<dim3(BT_TOK / 256), blk, 0, stream>>>(
        cand_v, cand_i, enorm, out, idxbuf, sums + 1, NT_VQ);

    pooled_k<<<dim3(64), blk, 0, stream>>>(idxbuf, codebook, pooled);

    // decoder layer 1 (bf16 MFMA, gathered codebook rows): dh = relu(Q @ dec_w1 + b)
    mfma_gemm_k<0><<<dim3(H1D / 128, BT_TOK / 128), blk, 0, stream>>>(
        cb_bf, w1T, dec_b1, dh_bf, nullptr, nullptr, idxbuf, H1D, H2D);

    // decoder layer 2 (bf16 MFMA) + fused recon loss
    mfma_gemm_k<1><<<dim3(D_IN / 128, BT_TOK / 128), blk, 0, stream>>>(
        dh_bf, w2T, dec_b2, nullptr, x, sums, nullptr, D_IN, H1D);

    proj_k<<<dim3(64), blk, 0, stream>>>(pooled, proj_w1, proj_b1, proj_w2, proj_b2, nproj);
    contrast_k<<<dim3(1), blk, 0, stream>>>(nproj, sums, out + BT_TOK);
}

// Round 3
// 1234.502 us; speedup vs baseline: 1.7828x; 1.3038x over previous
//
#include <hip/hip_runtime.h>
#include <math.h>

#define BT_TOK 32768
#define D_IN   1024
#define H1D    768
#define H2D    512
#define KCB    512

typedef short bf16x8 __attribute__((ext_vector_type(8)));
typedef _Float16 f16;
typedef _Float16 half8v __attribute__((ext_vector_type(8)));
typedef float f32x4 __attribute__((ext_vector_type(4)));

#define GLDS16(g, l) \
    __builtin_amdgcn_global_load_lds((const __attribute__((address_space(1))) void*)(g), \
                                     (__attribute__((address_space(3))) void*)(l), 16, 0, 0)

__device__ __forceinline__ unsigned short f2bf(float f) {
    union { float f; unsigned u; } v; v.f = f;
    const unsigned r = v.u + 0x7FFFu + ((v.u >> 16) & 1u);
    return (unsigned short)(r >> 16);
}

// split convention: hi = f16(v), lo = f16((v-hi)*2048); v ~= hi + lo/2048
__device__ __forceinline__ void splitf(float v, f16& h, f16& l) {
    h = (f16)v;
    l = (f16)((v - (float)h) * 2048.f);
}

// ---------------------------------------------------------------------------
// Split-FP16 MFMA GEMM: C = A @ B^T in ~fp32 precision via 3 MFMAs/tile.
// 128x128 block, 16x16x32 f16 MFMA, BK=32. Bh/Bl are [N][Kd] f16 pairs.
// XSPLIT: A is fp32 [M][Kd], split in-kernel. else: Ah/Al f16 pairs (GLDS).
// EPI 0: +bias, write f16 hi/lo pair (pre-LN). EPI 1: VQ tile-argmin
//        (cnorm[n] - 2*acc), cand slot = row*8 + blockIdx.x*2 + wn.
// ---------------------------------------------------------------------------
template<int EPI, bool XSPLIT>
__global__ __launch_bounds__(256) void sgemm_k(
    const float* __restrict__ Af,
    const f16* __restrict__ Ah, const f16* __restrict__ Al,
    const f16* __restrict__ Bh, const f16* __restrict__ Bl,
    const float* __restrict__ bias,
    f16* __restrict__ Ch, f16* __restrict__ Cl,
    const float* __restrict__ cnorm,
    float* __restrict__ cand_v, int* __restrict__ cand_i,
    int N, int Kd)
{
    __shared__ __align__(16) f16 sAh[128 * 32];
    __shared__ __align__(16) f16 sAl[128 * 32];
    __shared__ __align__(16) f16 sBh[128 * 32];
    __shared__ __align__(16) f16 sBl[128 * 32];

    const int t = threadIdx.x;
    const int lane = t & 63, wave = t >> 6;
    const int wm = wave & 1, wn = wave >> 1;
    const int row0 = blockIdx.y * 128, col0 = blockIdx.x * 128;

    f32x4 acc_h[4][4], acc_l[4][4];
#pragma unroll
    for (int i = 0; i < 4; ++i)
#pragma unroll
        for (int j = 0; j < 4; ++j) {
            acc_h[i][j] = (f32x4){0.f, 0.f, 0.f, 0.f};
            acc_l[i][j] = (f32x4){0.f, 0.f, 0.f, 0.f};
        }

    // GLDS staging coords (f16 matrices): row sr, 16B chunk sk8
    const int sr = t >> 2;
    const int sk8 = (t & 3) * 8;
    // XSPLIT A staging coords: row arow (2 threads/row), 16-float chunk ac
    const int arow = t >> 1;
    const int ac = (t & 1) * 16;

    const f16* gBh0 = Bh + (size_t)(col0 + sr) * Kd + sk8;
    const f16* gBh1 = Bh + (size_t)(col0 + 64 + sr) * Kd + sk8;
    const f16* gBl0 = Bl + (size_t)(col0 + sr) * Kd + sk8;
    const f16* gBl1 = Bl + (size_t)(col0 + 64 + sr) * Kd + sk8;
    const f16* gAh0 = nullptr; const f16* gAh1 = nullptr;
    const f16* gAl0 = nullptr; const f16* gAl1 = nullptr;
    const float* gAf = nullptr;
    if (XSPLIT) {
        gAf = Af + (size_t)(row0 + arow) * Kd + ac;
    } else {
        gAh0 = Ah + (size_t)(row0 + sr) * Kd + sk8;
        gAh1 = Ah + (size_t)(row0 + 64 + sr) * Kd + sk8;
        gAl0 = Al + (size_t)(row0 + sr) * Kd + sk8;
        gAl1 = Al + (size_t)(row0 + 64 + sr) * Kd + sk8;
    }

    char* dBh0 = (char*)sBh + wave * 1024;
    char* dBh1 = (char*)sBh + 4096 + wave * 1024;
    char* dBl0 = (char*)sBl + wave * 1024;
    char* dBl1 = (char*)sBl + 4096 + wave * 1024;
    char* dAh0 = (char*)sAh + wave * 1024;
    char* dAh1 = (char*)sAh + 4096 + wave * 1024;
    char* dAl0 = (char*)sAl + wave * 1024;
    char* dAl1 = (char*)sAl + 4096 + wave * 1024;

    const int fr = lane & 15;
    const int fq8 = (lane >> 4) * 8;   // f16 offset of k-chunk

    for (int k0 = 0; k0 < Kd; k0 += 32) {
        if (XSPLIT) {
            const float4* gp = (const float4*)(gAf + k0);
#pragma unroll
            for (int h8 = 0; h8 < 2; ++h8) {
                const float4 f0 = gp[h8 * 2];
                const float4 f1 = gp[h8 * 2 + 1];
                const float fv[8] = {f0.x, f0.y, f0.z, f0.w, f1.x, f1.y, f1.z, f1.w};
                f16 hv[8] __attribute__((aligned(16)));
                f16 lv[8] __attribute__((aligned(16)));
#pragma unroll
                for (int i = 0; i < 8; ++i) splitf(fv[i], hv[i], lv[i]);
                *(half8v*)(sAh + arow * 32 + ac + h8 * 8) = *(half8v*)hv;
                *(half8v*)(sAl + arow * 32 + ac + h8 * 8) = *(half8v*)lv;
            }
        } else {
            GLDS16(gAh0 + k0, dAh0);
            GLDS16(gAh1 + k0, dAh1);
            GLDS16(gAl0 + k0, dAl0);
            GLDS16(gAl1 + k0, dAl1);
        }
        GLDS16(gBh0 + k0, dBh0);
        GLDS16(gBh1 + k0, dBh1);
        GLDS16(gBl0 + k0, dBl0);
        GLDS16(gBl1 + k0, dBl1);
        __syncthreads();

        half8v fah[4], fal[4], fbh[4], fbl[4];
#pragma unroll
        for (int mi = 0; mi < 4; ++mi) {
            fah[mi] = *(const half8v*)(sAh + (wm * 64 + mi * 16 + fr) * 32 + fq8);
            fal[mi] = *(const half8v*)(sAl + (wm * 64 + mi * 16 + fr) * 32 + fq8);
        }
#pragma unroll
        for (int ni = 0; ni < 4; ++ni) {
            fbh[ni] = *(const half8v*)(sBh + (wn * 64 + ni * 16 + fr) * 32 + fq8);
            fbl[ni] = *(const half8v*)(sBl + (wn * 64 + ni * 16 + fr) * 32 + fq8);
        }
#pragma unroll
        for (int mi = 0; mi < 4; ++mi)
#pragma unroll
            for (int ni = 0; ni < 4; ++ni) {
                acc_h[mi][ni] = __builtin_amdgcn_mfma_f32_16x16x32_f16(
                    fah[mi], fbh[ni], acc_h[mi][ni], 0, 0, 0);
                acc_l[mi][ni] = __builtin_amdgcn_mfma_f32_16x16x32_f16(
                    fah[mi], fbl[ni], acc_l[mi][ni], 0, 0, 0);
                acc_l[mi][ni] = __builtin_amdgcn_mfma_f32_16x16x32_f16(
                    fal[mi], fbh[ni], acc_l[mi][ni], 0, 0, 0);
            }
        __syncthreads();
    }

    const int cR = (lane >> 4) * 4;   // C/D: row = quad*4 + reg, col = lane&15
    const int cC = lane & 15;

    if (EPI == 0) {
#pragma unroll
        for (int ni = 0; ni < 4; ++ni) {
            const int col = col0 + wn * 64 + ni * 16 + cC;
            const float bb = bias[col];
#pragma unroll
            for (int mi = 0; mi < 4; ++mi)
#pragma unroll
                for (int r = 0; r < 4; ++r) {
                    const size_t row = row0 + wm * 64 + mi * 16 + cR + r;
                    const float v = acc_h[mi][ni][r] + acc_l[mi][ni][r] * (1.f / 2048.f) + bb;
                    f16 vh, vl;
                    splitf(v, vh, vl);
                    Ch[row * N + col] = vh;
                    Cl[row * N + col] = vl;
                }
        }
    } else {
#pragma unroll
        for (int mi = 0; mi < 4; ++mi)
#pragma unroll
            for (int r = 0; r < 4; ++r) {
                float bestv = 1e30f;
                int besti = 0;
#pragma unroll
                for (int ni = 0; ni < 4; ++ni) {
                    const int col = col0 + wn * 64 + ni * 16 + cC;
                    const float v = cnorm[col]
                        - 2.f * (acc_h[mi][ni][r] + acc_l[mi][ni][r] * (1.f / 2048.f));
                    if (v < bestv || (v == bestv && col < besti)) { bestv = v; besti = col; }
                }
#pragma unroll
                for (int m = 1; m < 16; m <<= 1) {
                    const float ov = __shfl_xor(bestv, m);
                    const int oi = __shfl_xor(besti, m);
                    if (ov < bestv || (ov == bestv && oi < besti)) { bestv = ov; besti = oi; }
                }
                if (cC == 0) {
                    const size_t row = row0 + wm * 64 + mi * 16 + cR + r;
                    cand_v[row * 8 + blockIdx.x * 2 + wn] = bestv;
                    cand_i[row * 8 + blockIdx.x * 2 + wn] = besti;
                }
            }
    }
}

// ---------------------------------------------------------------------------
// bf16 MFMA GEMM for the decoder (loss path; 2% tolerance).
// ---------------------------------------------------------------------------
template<int EPI>
__global__ __launch_bounds__(256) void mfma_gemm_k(
    const unsigned short* __restrict__ A, const unsigned short* __restrict__ BT,
    const float* __restrict__ bias, unsigned short* __restrict__ Cbf,
    const float* __restrict__ Xref, float* __restrict__ lsum_out,
    const int* __restrict__ gidx, int N, int Kd)
{
    __shared__ __align__(16) unsigned short sA[128 * 32];
    __shared__ __align__(16) unsigned short sB[128 * 32];

    const int t = threadIdx.x;
    const int lane = t & 63, wave = t >> 6;
    const int wm = wave & 1, wn = wave >> 1;
    const int row0 = blockIdx.y * 128, col0 = blockIdx.x * 128;

    f32x4 acc[4][4];
#pragma unroll
    for (int i = 0; i < 4; ++i)
#pragma unroll
        for (int j = 0; j < 4; ++j) acc[i][j] = (f32x4){0.f, 0.f, 0.f, 0.f};

    const int sr = t >> 2;
    const int sk = (t & 3) * 8;

    int ar0 = row0 + sr, ar1 = row0 + 64 + sr;
    if (gidx) { ar0 = gidx[row0 + sr]; ar1 = gidx[row0 + 64 + sr]; }
    const unsigned short* gA0 = A + (size_t)ar0 * Kd + sk;
    const unsigned short* gA1 = A + (size_t)ar1 * Kd + sk;
    const unsigned short* gB0 = BT + (size_t)(col0 + sr) * Kd + sk;
    const unsigned short* gB1 = BT + (size_t)(col0 + 64 + sr) * Kd + sk;

    char* sAc = (char*)sA;
    char* sBc = (char*)sB;
    char* dA0 = sAc + wave * 1024;
    char* dA1 = sAc + 4096 + wave * 1024;
    char* dB0 = sBc + wave * 1024;
    char* dB1 = sBc + 4096 + wave * 1024;

    const int fr = lane & 15;
    const int fk = (lane >> 4) * 16;

    for (int k0 = 0; k0 < Kd; k0 += 32) {
        GLDS16(gA0 + k0, dA0);
        GLDS16(gA1 + k0, dA1);
        GLDS16(gB0 + k0, dB0);
        GLDS16(gB1 + k0, dB1);
        __syncthreads();

        bf16x8 a[4], b[4];
#pragma unroll
        for (int mi = 0; mi < 4; ++mi)
            a[mi] = *(const bf16x8*)(sAc + (size_t)(wm * 64 + mi * 16 + fr) * 64 + fk);
#pragma unroll
        for (int ni = 0; ni < 4; ++ni)
            b[ni] = *(const bf16x8*)(sBc + (size_t)(wn * 64 + ni * 16 + fr) * 64 + fk);
#pragma unroll
        for (int mi = 0; mi < 4; ++mi)
#pragma unroll
            for (int ni = 0; ni < 4; ++ni)
                acc[mi][ni] = __builtin_amdgcn_mfma_f32_16x16x32_bf16(
                    a[mi], b[ni], acc[mi][ni], 0, 0, 0);
        __syncthreads();
    }

    const int cR = (lane >> 4) * 4;
    const int cC = lane & 15;

    if (EPI == 0) {
#pragma unroll
        for (int ni = 0; ni < 4; ++ni) {
            const int col = col0 + wn * 64 + ni * 16 + cC;
            const float bb = bias[col];
#pragma unroll
            for (int mi = 0; mi < 4; ++mi)
#pragma unroll
                for (int r = 0; r < 4; ++r) {
                    const size_t row = row0 + wm * 64 + mi * 16 + cR + r;
                    const float v = fmaxf(acc[mi][ni][r] + bb, 0.f);
                    Cbf[row * N + col] = f2bf(v);
                }
        }
    } else {
        float ls = 0.f;
#pragma unroll
        for (int ni = 0; ni < 4; ++ni) {
            const int col = col0 + wn * 64 + ni * 16 + cC;
            const float bb = bias[col];
#pragma unroll
            for (int mi = 0; mi < 4; ++mi)
#pragma unroll
                for (int r = 0; r < 4; ++r) {
                    const size_t row = row0 + wm * 64 + mi * 16 + cR + r;
                    const float d = acc[mi][ni][r] + bb - Xref[row * N + col];
                    ls = fmaf(d, d, ls);
                }
        }
        __shared__ float red[256];
        red[t] = ls;
        __syncthreads();
        for (int s = 128; s > 0; s >>= 1) {
            if (t < s) red[t] += red[t + s];
            __syncthreads();
        }
        if (t == 0) atomicAdd(lsum_out, red[0]);
    }
}

// ---------------------------------------------------------------------------
// conversion / prep kernels
// ---------------------------------------------------------------------------
// dst pair [N][K] f16 = split(transpose(src[K][N] fp32))
__global__ __launch_bounds__(256) void splitT_k(const float* __restrict__ src,
                                                f16* __restrict__ dh, f16* __restrict__ dl,
                                                int K, int N)
{
    const int i = blockIdx.x * 256 + threadIdx.x;
    if (i < K * N) {
        const int n = i / K, k = i % K;
        const float v = src[(size_t)k * N + n];
        f16 h, l;
        splitf(v, h, l);
        dh[i] = h; dl[i] = l;
    }
}

__global__ __launch_bounds__(256) void split_k(const float* __restrict__ src,
                                               f16* __restrict__ dh, f16* __restrict__ dl,
                                               int n)
{
    const int i = blockIdx.x * 256 + threadIdx.x;
    if (i < n) {
        f16 h, l;
        splitf(src[i], h, l);
        dh[i] = h; dl[i] = l;
    }
}

__global__ __launch_bounds__(256) void convT_k(const float* __restrict__ src,
                                               unsigned short* __restrict__ dst,
                                               int K, int N)
{
    const int i = blockIdx.x * 256 + threadIdx.x;
    if (i < K * N) {
        const int n = i / K, k = i % K;
        dst[i] = f2bf(src[(size_t)k * N + n]);
    }
}

__global__ __launch_bounds__(256) void conv_k(const float* __restrict__ src,
                                              unsigned short* __restrict__ dst, int n)
{
    const int i = blockIdx.x * 256 + threadIdx.x;
    if (i < n) dst[i] = f2bf(src[i]);
}

// ---------------------------------------------------------------------------
// LayerNorm + ReLU on an f16 hi/lo pair (in place), fp32 math.
// ---------------------------------------------------------------------------
template<int H, bool ENORM>
__global__ __launch_bounds__(256) void ln_pair_k(
    f16* __restrict__ hi, f16* __restrict__ lo, const float* __restrict__ g,
    const float* __restrict__ b, float* __restrict__ enorm)
{
    constexpr int E = H / 64;
    const int lane = threadIdx.x & 63;
    const int wid = threadIdx.x >> 6;
    const size_t row = (size_t)blockIdx.x * 4 + wid;
    f16* ph = hi + row * H;
    f16* pl = lo + row * H;

    float h[E];
    float s = 0.f;
#pragma unroll
    for (int e = 0; e < E; ++e) {
        h[e] = (float)ph[lane + e * 64] + (float)pl[lane + e * 64] * (1.f / 2048.f);
        s += h[e];
    }
#pragma unroll
    for (int m = 1; m < 64; m <<= 1) s += __shfl_xor(s, m);
    const float mu = s * (1.f / H);

    float vs = 0.f;
#pragma unroll
    for (int e = 0; e < E; ++e) { const float d = h[e] - mu; vs = fmaf(d, d, vs); }
#pragma unroll
    for (int m = 1; m < 64; m <<= 1) vs += __shfl_xor(vs, m);
    const float rstd = rsqrtf(vs * (1.f / H) + 1e-5f);

    float q = 0.f;
#pragma unroll
    for (int e = 0; e < E; ++e) {
        float o = (h[e] - mu) * rstd * g[lane + e * 64] + b[lane + e * 64];
        o = fmaxf(o, 0.f);
        f16 oh, ol;
        splitf(o, oh, ol);
        ph[lane + e * 64] = oh;
        pl[lane + e * 64] = ol;
        q = fmaf(o, o, q);
    }
    if (ENORM) {
#pragma unroll
        for (int m = 1; m < 64; m <<= 1) q += __shfl_xor(q, m);
        if (lane == 0) enorm[row] = q;
    }
}

__global__ __launch_bounds__(256) void rowsumsq_k(const float* __restrict__ A,
                                                  float* __restrict__ out)
{
    const int lane = threadIdx.x & 63;
    const int wid = threadIdx.x >> 6;
    const size_t row = (size_t)blockIdx.x * 4 + wid;
    const float* p = A + row * 512;
    float s = 0.f;
#pragma unroll
    for (int e = 0; e < 8; ++e) { const float v = p[lane + e * 64]; s = fmaf(v, v, s); }
#pragma unroll
    for (int m = 1; m < 64; m <<= 1) s += __shfl_xor(s, m);
    if (lane == 0) out[row] = s;
}

__global__ __launch_bounds__(256) void vq_reduce_k(
    const float* __restrict__ cand_v, const int* __restrict__ cand_i,
    const float* __restrict__ enorm, float* __restrict__ out_idx_f,
    int* __restrict__ out_idx, float* __restrict__ commit_sum, int ntiles)
{
    const int tid = threadIdx.x;
    const int m = blockIdx.x * 256 + tid;
    float bv = cand_v[(size_t)m * ntiles];
    int bi = cand_i[(size_t)m * ntiles];
    for (int t = 1; t < ntiles; ++t) {
        const float v = cand_v[(size_t)m * ntiles + t];
        const int i = cand_i[(size_t)m * ntiles + t];
        if (v < bv) { bv = v; bi = i; }
    }
    out_idx_f[m] = (float)bi;
    out_idx[m] = bi;
    const float d2 = enorm[m] + bv;

    __shared__ float red[256];
    red[tid] = d2;
    __syncthreads();
    for (int s = 128; s > 0; s >>= 1) {
        if (tid < s) red[tid] += red[tid + s];
        __syncthreads();
    }
    if (tid == 0) atomicAdd(commit_sum, red[0]);
}

__global__ __launch_bounds__(256) void pooled_k(const int* __restrict__ idx,
                                                const float* __restrict__ cb,
                                                float* __restrict__ pooled)
{
    const int b = blockIdx.x;
    const int d = threadIdx.x;
    float a0 = 0.f, a1 = 0.f;
    for (int t = 0; t < 512; ++t) {
        const int id = idx[b * 512 + t];
        a0 += cb[(size_t)id * 512 + d];
        a1 += cb[(size_t)id * 512 + d + 256];
    }
    pooled[b * 512 + d] = a0 * (1.f / 512.f);
    pooled[b * 512 + d + 256] = a1 * (1.f / 512.f);
}

__global__ __launch_bounds__(256) void proj_k(
    const float* __restrict__ pooled, const float* __restrict__ w1,
    const float* __restrict__ b1, const float* __restrict__ w2,
    const float* __restrict__ b2, float* __restrict__ nproj)
{
    __shared__ float sp[512];
    __shared__ float sh[256];
    __shared__ float red[128];
    const int b = blockIdx.x, tid = threadIdx.x;
    sp[tid] = pooled[b * 512 + tid];
    sp[tid + 256] = pooled[b * 512 + tid + 256];
    __syncthreads();

    float acc = b1[tid];
    for (int k = 0; k < 512; ++k) acc = fmaf(sp[k], w1[k * 256 + tid], acc);
    sh[tid] = fmaxf(acc, 0.f);
    __syncthreads();

    float p = 0.f;
    if (tid < 128) {
        p = b2[tid];
        for (int k = 0; k < 256; ++k) p = fmaf(sh[k], w2[k * 128 + tid], p);
        red[tid] = p * p;
    }
    __syncthreads();
    for (int s = 64; s > 0; s >>= 1) {
        if (tid < s) red[tid] += red[tid + s];
        __syncthreads();
    }
    if (tid < 128) {
        const float nrm = fmaxf(sqrtf(red[0]), 1e-12f);
        nproj[b * 128 + tid] = p / nrm;
    }
}

__global__ __launch_bounds__(256) void contrast_k(
    const float* __restrict__ nproj, const float* __restrict__ sums,
    float* __restrict__ out5)
{
    __shared__ float s_np[64 * 128];
    __shared__ float s_sim[64 * 64];
    __shared__ float s_row[64];
    const int tid = threadIdx.x;
    for (int i = tid; i < 64 * 128; i += 256) s_np[i] = nproj[i];
    __syncthreads();
    for (int p = tid; p < 64 * 64; p += 256) {
        const int i = p >> 6, j = p & 63;
        float d = 0.f;
        for (int k = 0; k < 128; ++k) d = fmaf(s_np[i * 128 + k], s_np[j * 128 + k], d);
        s_sim[p] = d * 10.f;
    }
    __syncthreads();
    if (tid < 64) {
        float mx = -1e30f;
        for (int j = 0; j < 64; ++j) mx = fmaxf(mx, s_sim[tid * 64 + j]);
        float se = 0.f;
        for (int j = 0; j < 64; ++j) se += expf(s_sim[tid * 64 + j] - mx);
        const float lse = mx + logf(se);
        s_row[tid] = s_sim[tid * 64 + tid] - lse;
    }
    __syncthreads();
    if (tid == 0) {
        float c = 0.f;
        for (int i = 0; i < 64; ++i) c += s_row[i];
        const float contr = -c / 64.f;
        const float recon = sums[0] / ((float)BT_TOK * (float)D_IN);
        const float commit = sums[1] / ((float)BT_TOK * (float)H2D);
        const float cbl = commit;
        const float total = recon * 1.0f + commit * 1.0f + cbl * 0.25f + contr * 0.5f;
        out5[0] = total;
        out5[1] = recon;
        out5[2] = commit;
        out5[3] = cbl;
        out5[4] = contr;
    }
}

__global__ void init_k(float* sums)
{
    if (threadIdx.x < 2) sums[threadIdx.x] = 0.f;
}

extern "C" void kernel_launch(void* const* d_in, const int* in_sizes, int n_in,
                              void* d_out, int out_size, void* d_ws, size_t ws_size,
                              hipStream_t stream)
{
    const float* x       = (const float*)d_in[0];
    const float* enc_w1  = (const float*)d_in[1];
    const float* enc_b1  = (const float*)d_in[2];
    const float* ln1_g   = (const float*)d_in[3];
    const float* ln1_b   = (const float*)d_in[4];
    const float* enc_w2  = (const float*)d_in[5];
    const float* enc_b2  = (const float*)d_in[6];
    const float* ln2_g   = (const float*)d_in[7];
    const float* ln2_b   = (const float*)d_in[8];
    const float* codebook= (const float*)d_in[9];
    const float* dec_w1  = (const float*)d_in[10];
    const float* dec_b1  = (const float*)d_in[11];
    const float* dec_w2  = (const float*)d_in[12];
    const float* dec_b2  = (const float*)d_in[13];
    const float* proj_w1 = (const float*)d_in[14];
    const float* proj_b1 = (const float*)d_in[15];
    const float* proj_w2 = (const float*)d_in[16];
    const float* proj_b2 = (const float*)d_in[17];
    float* out = (float*)d_out;

    char* wsb = (char*)d_ws;
    size_t off = 0;
    auto alloc = [&](size_t bytes) {
        void* p = wsb + off;
        off += (bytes + 255) & ~(size_t)255;
        return p;
    };

    f16* h1h  = (f16*)alloc((size_t)BT_TOK * H1D * 2);   // also dh_bf alias later
    f16* h1l  = (f16*)alloc((size_t)BT_TOK * H1D * 2);
    f16* ench = (f16*)alloc((size_t)BT_TOK * H2D * 2);
    f16* encl = (f16*)alloc((size_t)BT_TOK * H2D * 2);
    f16* w1h  = (f16*)alloc((size_t)H1D * D_IN * 2);
    f16* w1l  = (f16*)alloc((size_t)H1D * D_IN * 2);
    f16* w2h  = (f16*)alloc((size_t)H2D * H1D * 2);
    f16* w2l  = (f16*)alloc((size_t)H2D * H1D * 2);
    f16* cbh  = (f16*)alloc((size_t)KCB * H2D * 2);
    f16* cbl  = (f16*)alloc((size_t)KCB * H2D * 2);
    unsigned short* cb_bf = (unsigned short*)alloc((size_t)KCB * H2D * 2);
    unsigned short* w1Td  = (unsigned short*)alloc((size_t)H1D * H2D * 2);
    unsigned short* w2Td  = (unsigned short*)alloc((size_t)D_IN * H1D * 2);
    float* cnorm  = (float*)alloc(KCB * 4);
    float* enorm  = (float*)alloc(BT_TOK * 4);
    float* cand_v = (float*)alloc((size_t)BT_TOK * 8 * 4);
    int*   cand_i = (int*)alloc((size_t)BT_TOK * 8 * 4);
    int*   idxbuf = (int*)alloc(BT_TOK * 4);
    float* pooled = (float*)alloc(64 * 512 * 4);
    float* nproj  = (float*)alloc(64 * 128 * 4);
    float* sums   = (float*)alloc(2 * 4);
    // decoder hidden bf16 [32768][768] aliases h1h (dead after encoder GEMM2)
    unsigned short* dh_bf = (unsigned short*)h1h;

    const dim3 blk(256);

    hipLaunchKernelGGL(init_k, dim3(1), blk, 0, stream, sums);

    // weight prep (tiny)
    splitT_k<<<dim3((H1D * D_IN + 255) / 256), blk, 0, stream>>>(enc_w1, w1h, w1l, D_IN, H1D);
    splitT_k<<<dim3((H2D * H1D + 255) / 256), blk, 0, stream>>>(enc_w2, w2h, w2l, H1D, H2D);
    split_k<<<dim3((KCB * H2D + 255) / 256), blk, 0, stream>>>(codebook, cbh, cbl, KCB * H2D);
    conv_k<<<dim3((KCB * H2D + 255) / 256), blk, 0, stream>>>(codebook, cb_bf, KCB * H2D);
    convT_k<<<dim3((H1D * H2D + 255) / 256), blk, 0, stream>>>(dec_w1, w1Td, H2D, H1D);
    convT_k<<<dim3((D_IN * H1D + 255) / 256), blk, 0, stream>>>(dec_w2, w2Td, H1D, D_IN);
    rowsumsq_k<<<dim3(KCB / 4), blk, 0, stream>>>(codebook, cnorm);

    // encoder layer 1 (split-fp16 MFMA, x split in-kernel): h1 = x @ enc_w1 + b1
    sgemm_k<0, true><<<dim3(H1D / 128, BT_TOK / 128), blk, 0, stream>>>(
        x, nullptr, nullptr, w1h, w1l, enc_b1, h1h, h1l, nullptr, nullptr, nullptr,
        H1D, D_IN);
    ln_pair_k<H1D, false><<<dim3(BT_TOK / 4), blk, 0, stream>>>(h1h, h1l, ln1_g, ln1_b, nullptr);

    // encoder layer 2: enc = h1 @ enc_w2 + b2
    sgemm_k<0, false><<<dim3(H2D / 128, BT_TOK / 128), blk, 0, stream>>>(
        nullptr, h1h, h1l, w2h, w2l, enc_b2, ench, encl, nullptr, nullptr, nullptr,
        H2D, H1D);
    ln_pair_k<H2D, true><<<dim3(BT_TOK / 4), blk, 0, stream>>>(ench, encl, ln2_g, ln2_b, enorm);

    // VQ scores + tile argmin
    sgemm_k<1, false><<<dim3(KCB / 128, BT_TOK / 128), blk, 0, stream>>>(
        nullptr, ench, encl, cbh, cbl, nullptr, nullptr, nullptr, cnorm, cand_v, cand_i,
        KCB, H2D);
    vq_reduce_k<<<dim3(BT_TOK / 256), blk, 0, stream>>>(
        cand_v, cand_i, enorm, out, idxbuf, sums + 1, 8);

    pooled_k<<<dim3(64), blk, 0, stream>>>(idxbuf, codebook, pooled);

    // decoder (bf16 MFMA)
    mfma_gemm_k<0><<<dim3(H1D / 128, BT_TOK / 128), blk, 0, stream>>>(
        cb_bf, w1Td, dec_b1, dh_bf, nullptr, nullptr, idxbuf, H1D, H2D);
    mfma_gemm_k<1><<<dim3(D_IN / 128, BT_TOK / 128), blk, 0, stream>>>(
        dh_bf, w2Td, dec_b2, nullptr, x, sums, nullptr, D_IN, H1D);

    proj_k<<<dim3(64), blk, 0, stream>>>(pooled, proj_w1, proj_b1, proj_w2, proj_b2, nproj);
    contrast_k<<<dim3(1), blk, 0, stream>>>(nproj, sums, out + BT_TOK);
}

// Round 4
// 880.702 us; speedup vs baseline: 2.4990x; 1.4017x over previous
//
#include <hip/hip_runtime.h>
#include <math.h>

#define BT_TOK 32768
#define D_IN   1024
#define H1D    768
#define H2D    512
#define KCB    512

typedef short bf16x8 __attribute__((ext_vector_type(8)));
typedef _Float16 f16;
typedef _Float16 half8v __attribute__((ext_vector_type(8)));
typedef float f32x4 __attribute__((ext_vector_type(4)));

#define GLDS16(g, l) \
    __builtin_amdgcn_global_load_lds((const __attribute__((address_space(1))) void*)(g), \
                                     (__attribute__((address_space(3))) void*)(l), 16, 0, 0)

__device__ __forceinline__ unsigned short f2bf(float f) {
    union { float f; unsigned u; } v; v.f = f;
    const unsigned r = v.u + 0x7FFFu + ((v.u >> 16) & 1u);
    return (unsigned short)(r >> 16);
}

// split convention: hi = f16(v), lo = f16((v-hi)*2048); v ~= hi + lo/2048
__device__ __forceinline__ void splitf(float v, f16& h, f16& l) {
    h = (f16)v;
    l = (f16)((v - (float)h) * 2048.f);
}

// ---------------------------------------------------------------------------
// Split-FP16 MFMA GEMM: C = A @ B^T in ~fp32 precision via 3 MFMAs/tile.
// 128x128 block, 16x16x32 f16 MFMA, BK=32. Bh/Bl are [N][Kd] f16 pairs.
// __launch_bounds__(256,2): cap unified VGPR+AGPR at 256 so 2 waves/SIMD
// stay resident (round-3 counters: 288 regs -> 1 wave/SIMD, Occ 11.7%).
// XSPLIT: A is fp32 [M][Kd], split in-kernel. else: Ah/Al f16 pairs (GLDS).
// EPI 0: +bias, write f16 hi/lo pair. EPI 1: VQ tile-argmin.
// ---------------------------------------------------------------------------
template<int EPI, bool XSPLIT>
__global__ __launch_bounds__(256, 2) void sgemm_k(
    const float* __restrict__ Af,
    const f16* __restrict__ Ah, const f16* __restrict__ Al,
    const f16* __restrict__ Bh, const f16* __restrict__ Bl,
    const float* __restrict__ bias,
    f16* __restrict__ Ch, f16* __restrict__ Cl,
    const float* __restrict__ cnorm,
    float* __restrict__ cand_v, int* __restrict__ cand_i,
    int N, int Kd)
{
    __shared__ __align__(16) f16 sAh[128 * 32];
    __shared__ __align__(16) f16 sAl[128 * 32];
    __shared__ __align__(16) f16 sBh[128 * 32];
    __shared__ __align__(16) f16 sBl[128 * 32];

    const int t = threadIdx.x;
    const int lane = t & 63, wave = t >> 6;
    const int wm = wave & 1, wn = wave >> 1;
    const int row0 = blockIdx.y * 128, col0 = blockIdx.x * 128;

    f32x4 acc_h[4][4], acc_l[4][4];
#pragma unroll
    for (int i = 0; i < 4; ++i)
#pragma unroll
        for (int j = 0; j < 4; ++j) {
            acc_h[i][j] = (f32x4){0.f, 0.f, 0.f, 0.f};
            acc_l[i][j] = (f32x4){0.f, 0.f, 0.f, 0.f};
        }

    const int sr = t >> 2;
    const int sk8 = (t & 3) * 8;
    const int arow = t >> 1;
    const int ac = (t & 1) * 16;

    const f16* gBh0 = Bh + (size_t)(col0 + sr) * Kd + sk8;
    const f16* gBh1 = Bh + (size_t)(col0 + 64 + sr) * Kd + sk8;
    const f16* gBl0 = Bl + (size_t)(col0 + sr) * Kd + sk8;
    const f16* gBl1 = Bl + (size_t)(col0 + 64 + sr) * Kd + sk8;
    const f16* gAh0 = nullptr; const f16* gAh1 = nullptr;
    const f16* gAl0 = nullptr; const f16* gAl1 = nullptr;
    const float* gAf = nullptr;
    if (XSPLIT) {
        gAf = Af + (size_t)(row0 + arow) * Kd + ac;
    } else {
        gAh0 = Ah + (size_t)(row0 + sr) * Kd + sk8;
        gAh1 = Ah + (size_t)(row0 + 64 + sr) * Kd + sk8;
        gAl0 = Al + (size_t)(row0 + sr) * Kd + sk8;
        gAl1 = Al + (size_t)(row0 + 64 + sr) * Kd + sk8;
    }

    char* dBh0 = (char*)sBh + wave * 1024;
    char* dBh1 = (char*)sBh + 4096 + wave * 1024;
    char* dBl0 = (char*)sBl + wave * 1024;
    char* dBl1 = (char*)sBl + 4096 + wave * 1024;
    char* dAh0 = (char*)sAh + wave * 1024;
    char* dAh1 = (char*)sAh + 4096 + wave * 1024;
    char* dAl0 = (char*)sAl + wave * 1024;
    char* dAl1 = (char*)sAl + 4096 + wave * 1024;

    const int fr = lane & 15;
    const int fq8 = (lane >> 4) * 8;

    for (int k0 = 0; k0 < Kd; k0 += 32) {
        if (XSPLIT) {
            const float4* gp = (const float4*)(gAf + k0);
#pragma unroll
            for (int h8 = 0; h8 < 2; ++h8) {
                const float4 f0 = gp[h8 * 2];
                const float4 f1 = gp[h8 * 2 + 1];
                const float fv[8] = {f0.x, f0.y, f0.z, f0.w, f1.x, f1.y, f1.z, f1.w};
                f16 hv[8] __attribute__((aligned(16)));
                f16 lv[8] __attribute__((aligned(16)));
#pragma unroll
                for (int i = 0; i < 8; ++i) splitf(fv[i], hv[i], lv[i]);
                *(half8v*)(sAh + arow * 32 + ac + h8 * 8) = *(half8v*)hv;
                *(half8v*)(sAl + arow * 32 + ac + h8 * 8) = *(half8v*)lv;
            }
        } else {
            GLDS16(gAh0 + k0, dAh0);
            GLDS16(gAh1 + k0, dAh1);
            GLDS16(gAl0 + k0, dAl0);
            GLDS16(gAl1 + k0, dAl1);
        }
        GLDS16(gBh0 + k0, dBh0);
        GLDS16(gBh1 + k0, dBh1);
        GLDS16(gBl0 + k0, dBl0);
        GLDS16(gBl1 + k0, dBl1);
        __syncthreads();

        // A-fragments held across the ni loop; B-fragments loaded per ni to
        // keep live ranges short (reg budget: acc 128 + A 32 + B 8 + addr)
        half8v fah[4], fal[4];
#pragma unroll
        for (int mi = 0; mi < 4; ++mi) {
            fah[mi] = *(const half8v*)(sAh + (wm * 64 + mi * 16 + fr) * 32 + fq8);
            fal[mi] = *(const half8v*)(sAl + (wm * 64 + mi * 16 + fr) * 32 + fq8);
        }
#pragma unroll
        for (int ni = 0; ni < 4; ++ni) {
            const half8v fbh = *(const half8v*)(sBh + (wn * 64 + ni * 16 + fr) * 32 + fq8);
            const half8v fbl = *(const half8v*)(sBl + (wn * 64 + ni * 16 + fr) * 32 + fq8);
#pragma unroll
            for (int mi = 0; mi < 4; ++mi) {
                acc_h[mi][ni] = __builtin_amdgcn_mfma_f32_16x16x32_f16(
                    fah[mi], fbh, acc_h[mi][ni], 0, 0, 0);
                acc_l[mi][ni] = __builtin_amdgcn_mfma_f32_16x16x32_f16(
                    fah[mi], fbl, acc_l[mi][ni], 0, 0, 0);
                acc_l[mi][ni] = __builtin_amdgcn_mfma_f32_16x16x32_f16(
                    fal[mi], fbh, acc_l[mi][ni], 0, 0, 0);
            }
        }
        __syncthreads();
    }

    const int cR = (lane >> 4) * 4;   // C/D: row = quad*4 + reg, col = lane&15
    const int cC = lane & 15;

    if (EPI == 0) {
#pragma unroll
        for (int ni = 0; ni < 4; ++ni) {
            const int col = col0 + wn * 64 + ni * 16 + cC;
            const float bb = bias[col];
#pragma unroll
            for (int mi = 0; mi < 4; ++mi)
#pragma unroll
                for (int r = 0; r < 4; ++r) {
                    const size_t row = row0 + wm * 64 + mi * 16 + cR + r;
                    const float v = acc_h[mi][ni][r] + acc_l[mi][ni][r] * (1.f / 2048.f) + bb;
                    f16 vh, vl;
                    splitf(v, vh, vl);
                    Ch[row * N + col] = vh;
                    Cl[row * N + col] = vl;
                }
        }
    } else {
#pragma unroll
        for (int mi = 0; mi < 4; ++mi)
#pragma unroll
            for (int r = 0; r < 4; ++r) {
                float bestv = 1e30f;
                int besti = 0;
#pragma unroll
                for (int ni = 0; ni < 4; ++ni) {
                    const int col = col0 + wn * 64 + ni * 16 + cC;
                    const float v = cnorm[col]
                        - 2.f * (acc_h[mi][ni][r] + acc_l[mi][ni][r] * (1.f / 2048.f));
                    if (v < bestv || (v == bestv && col < besti)) { bestv = v; besti = col; }
                }
#pragma unroll
                for (int m = 1; m < 16; m <<= 1) {
                    const float ov = __shfl_xor(bestv, m);
                    const int oi = __shfl_xor(besti, m);
                    if (ov < bestv || (ov == bestv && oi < besti)) { bestv = ov; besti = oi; }
                }
                if (cC == 0) {
                    const size_t row = row0 + wm * 64 + mi * 16 + cR + r;
                    cand_v[row * 8 + blockIdx.x * 2 + wn] = bestv;
                    cand_i[row * 8 + blockIdx.x * 2 + wn] = besti;
                }
            }
    }
}

// ---------------------------------------------------------------------------
// bf16 MFMA GEMM for the decoder (loss path; 2% tolerance).
// ---------------------------------------------------------------------------
template<int EPI>
__global__ __launch_bounds__(256, 2) void mfma_gemm_k(
    const unsigned short* __restrict__ A, const unsigned short* __restrict__ BT,
    const float* __restrict__ bias, unsigned short* __restrict__ Cbf,
    const float* __restrict__ Xref, float* __restrict__ lsum_out,
    const int* __restrict__ gidx, int N, int Kd)
{
    __shared__ __align__(16) unsigned short sA[128 * 32];
    __shared__ __align__(16) unsigned short sB[128 * 32];

    const int t = threadIdx.x;
    const int lane = t & 63, wave = t >> 6;
    const int wm = wave & 1, wn = wave >> 1;
    const int row0 = blockIdx.y * 128, col0 = blockIdx.x * 128;

    f32x4 acc[4][4];
#pragma unroll
    for (int i = 0; i < 4; ++i)
#pragma unroll
        for (int j = 0; j < 4; ++j) acc[i][j] = (f32x4){0.f, 0.f, 0.f, 0.f};

    const int sr = t >> 2;
    const int sk = (t & 3) * 8;

    int ar0 = row0 + sr, ar1 = row0 + 64 + sr;
    if (gidx) { ar0 = gidx[row0 + sr]; ar1 = gidx[row0 + 64 + sr]; }
    const unsigned short* gA0 = A + (size_t)ar0 * Kd + sk;
    const unsigned short* gA1 = A + (size_t)ar1 * Kd + sk;
    const unsigned short* gB0 = BT + (size_t)(col0 + sr) * Kd + sk;
    const unsigned short* gB1 = BT + (size_t)(col0 + 64 + sr) * Kd + sk;

    char* sAc = (char*)sA;
    char* sBc = (char*)sB;
    char* dA0 = sAc + wave * 1024;
    char* dA1 = sAc + 4096 + wave * 1024;
    char* dB0 = sBc + wave * 1024;
    char* dB1 = sBc + 4096 + wave * 1024;

    const int fr = lane & 15;
    const int fk = (lane >> 4) * 16;

    for (int k0 = 0; k0 < Kd; k0 += 32) {
        GLDS16(gA0 + k0, dA0);
        GLDS16(gA1 + k0, dA1);
        GLDS16(gB0 + k0, dB0);
        GLDS16(gB1 + k0, dB1);
        __syncthreads();

        bf16x8 a[4];
#pragma unroll
        for (int mi = 0; mi < 4; ++mi)
            a[mi] = *(const bf16x8*)(sAc + (size_t)(wm * 64 + mi * 16 + fr) * 64 + fk);
#pragma unroll
        for (int ni = 0; ni < 4; ++ni) {
            const bf16x8 b = *(const bf16x8*)(sBc + (size_t)(wn * 64 + ni * 16 + fr) * 64 + fk);
#pragma unroll
            for (int mi = 0; mi < 4; ++mi)
                acc[mi][ni] = __builtin_amdgcn_mfma_f32_16x16x32_bf16(
                    a[mi], b, acc[mi][ni], 0, 0, 0);
        }
        __syncthreads();
    }

    const int cR = (lane >> 4) * 4;
    const int cC = lane & 15;

    if (EPI == 0) {
#pragma unroll
        for (int ni = 0; ni < 4; ++ni) {
            const int col = col0 + wn * 64 + ni * 16 + cC;
            const float bb = bias[col];
#pragma unroll
            for (int mi = 0; mi < 4; ++mi)
#pragma unroll
                for (int r = 0; r < 4; ++r) {
                    const size_t row = row0 + wm * 64 + mi * 16 + cR + r;
                    const float v = fmaxf(acc[mi][ni][r] + bb, 0.f);
                    Cbf[row * N + col] = f2bf(v);
                }
        }
    } else {
        float ls = 0.f;
#pragma unroll
        for (int ni = 0; ni < 4; ++ni) {
            const int col = col0 + wn * 64 + ni * 16 + cC;
            const float bb = bias[col];
#pragma unroll
            for (int mi = 0; mi < 4; ++mi)
#pragma unroll
                for (int r = 0; r < 4; ++r) {
                    const size_t row = row0 + wm * 64 + mi * 16 + cR + r;
                    const float d = acc[mi][ni][r] + bb - Xref[row * N + col];
                    ls = fmaf(d, d, ls);
                }
        }
        __shared__ float red[256];
        red[t] = ls;
        __syncthreads();
        for (int s = 128; s > 0; s >>= 1) {
            if (t < s) red[t] += red[t + s];
            __syncthreads();
        }
        if (t == 0) atomicAdd(lsum_out, red[0]);
    }
}

// ---------------------------------------------------------------------------
// conversion / prep kernels
// ---------------------------------------------------------------------------
__global__ __launch_bounds__(256) void splitT_k(const float* __restrict__ src,
                                                f16* __restrict__ dh, f16* __restrict__ dl,
                                                int K, int N)
{
    const int i = blockIdx.x * 256 + threadIdx.x;
    if (i < K * N) {
        const int n = i / K, k = i % K;
        const float v = src[(size_t)k * N + n];
        f16 h, l;
        splitf(v, h, l);
        dh[i] = h; dl[i] = l;
    }
}

__global__ __launch_bounds__(256) void split_k(const float* __restrict__ src,
                                               f16* __restrict__ dh, f16* __restrict__ dl,
                                               int n)
{
    const int i = blockIdx.x * 256 + threadIdx.x;
    if (i < n) {
        f16 h, l;
        splitf(src[i], h, l);
        dh[i] = h; dl[i] = l;
    }
}

__global__ __launch_bounds__(256) void convT_k(const float* __restrict__ src,
                                               unsigned short* __restrict__ dst,
                                               int K, int N)
{
    const int i = blockIdx.x * 256 + threadIdx.x;
    if (i < K * N) {
        const int n = i / K, k = i % K;
        dst[i] = f2bf(src[(size_t)k * N + n]);
    }
}

__global__ __launch_bounds__(256) void conv_k(const float* __restrict__ src,
                                              unsigned short* __restrict__ dst, int n)
{
    const int i = blockIdx.x * 256 + threadIdx.x;
    if (i < n) dst[i] = f2bf(src[i]);
}

// ---------------------------------------------------------------------------
// LayerNorm + ReLU on an f16 hi/lo pair (in place), fp32 math.
// ---------------------------------------------------------------------------
template<int H, bool ENORM>
__global__ __launch_bounds__(256) void ln_pair_k(
    f16* __restrict__ hi, f16* __restrict__ lo, const float* __restrict__ g,
    const float* __restrict__ b, float* __restrict__ enorm)
{
    constexpr int E = H / 64;
    const int lane = threadIdx.x & 63;
    const int wid = threadIdx.x >> 6;
    const size_t row = (size_t)blockIdx.x * 4 + wid;
    f16* ph = hi + row * H;
    f16* pl = lo + row * H;

    float h[E];
    float s = 0.f;
#pragma unroll
    for (int e = 0; e < E; ++e) {
        h[e] = (float)ph[lane + e * 64] + (float)pl[lane + e * 64] * (1.f / 2048.f);
        s += h[e];
    }
#pragma unroll
    for (int m = 1; m < 64; m <<= 1) s += __shfl_xor(s, m);
    const float mu = s * (1.f / H);

    float vs = 0.f;
#pragma unroll
    for (int e = 0; e < E; ++e) { const float d = h[e] - mu; vs = fmaf(d, d, vs); }
#pragma unroll
    for (int m = 1; m < 64; m <<= 1) vs += __shfl_xor(vs, m);
    const float rstd = rsqrtf(vs * (1.f / H) + 1e-5f);

    float q = 0.f;
#pragma unroll
    for (int e = 0; e < E; ++e) {
        float o = (h[e] - mu) * rstd * g[lane + e * 64] + b[lane + e * 64];
        o = fmaxf(o, 0.f);
        f16 oh, ol;
        splitf(o, oh, ol);
        ph[lane + e * 64] = oh;
        pl[lane + e * 64] = ol;
        q = fmaf(o, o, q);
    }
    if (ENORM) {
#pragma unroll
        for (int m = 1; m < 64; m <<= 1) q += __shfl_xor(q, m);
        if (lane == 0) enorm[row] = q;
    }
}

__global__ __launch_bounds__(256) void rowsumsq_k(const float* __restrict__ A,
                                                  float* __restrict__ out)
{
    const int lane = threadIdx.x & 63;
    const int wid = threadIdx.x >> 6;
    const size_t row = (size_t)blockIdx.x * 4 + wid;
    const float* p = A + row * 512;
    float s = 0.f;
#pragma unroll
    for (int e = 0; e < 8; ++e) { const float v = p[lane + e * 64]; s = fmaf(v, v, s); }
#pragma unroll
    for (int m = 1; m < 64; m <<= 1) s += __shfl_xor(s, m);
    if (lane == 0) out[row] = s;
}

__global__ __launch_bounds__(256) void vq_reduce_k(
    const float* __restrict__ cand_v, const int* __restrict__ cand_i,
    const float* __restrict__ enorm, float* __restrict__ out_idx_f,
    int* __restrict__ out_idx, float* __restrict__ commit_sum, int ntiles)
{
    const int tid = threadIdx.x;
    const int m = blockIdx.x * 256 + tid;
    float bv = cand_v[(size_t)m * ntiles];
    int bi = cand_i[(size_t)m * ntiles];
    for (int t = 1; t < ntiles; ++t) {
        const float v = cand_v[(size_t)m * ntiles + t];
        const int i = cand_i[(size_t)m * ntiles + t];
        if (v < bv) { bv = v; bi = i; }
    }
    out_idx_f[m] = (float)bi;
    out_idx[m] = bi;
    const float d2 = enorm[m] + bv;

    __shared__ float red[256];
    red[tid] = d2;
    __syncthreads();
    for (int s = 128; s > 0; s >>= 1) {
        if (tid < s) red[tid] += red[tid + s];
        __syncthreads();
    }
    if (tid == 0) atomicAdd(commit_sum, red[0]);
}

__global__ __launch_bounds__(256) void pooled_k(const int* __restrict__ idx,
                                                const float* __restrict__ cb,
                                                float* __restrict__ pooled)
{
    const int b = blockIdx.x;
    const int d = threadIdx.x;
    float a0 = 0.f, a1 = 0.f;
    for (int t = 0; t < 512; ++t) {
        const int id = idx[b * 512 + t];
        a0 += cb[(size_t)id * 512 + d];
        a1 += cb[(size_t)id * 512 + d + 256];
    }
    pooled[b * 512 + d] = a0 * (1.f / 512.f);
    pooled[b * 512 + d + 256] = a1 * (1.f / 512.f);
}

__global__ __launch_bounds__(256) void proj_k(
    const float* __restrict__ pooled, const float* __restrict__ w1,
    const float* __restrict__ b1, const float* __restrict__ w2,
    const float* __restrict__ b2, float* __restrict__ nproj)
{
    __shared__ float sp[512];
    __shared__ float sh[256];
    __shared__ float red[128];
    const int b = blockIdx.x, tid = threadIdx.x;
    sp[tid] = pooled[b * 512 + tid];
    sp[tid + 256] = pooled[b * 512 + tid + 256];
    __syncthreads();

    float acc = b1[tid];
    for (int k = 0; k < 512; ++k) acc = fmaf(sp[k], w1[k * 256 + tid], acc);
    sh[tid] = fmaxf(acc, 0.f);
    __syncthreads();

    float p = 0.f;
    if (tid < 128) {
        p = b2[tid];
        for (int k = 0; k < 256; ++k) p = fmaf(sh[k], w2[k * 128 + tid], p);
        red[tid] = p * p;
    }
    __syncthreads();
    for (int s = 64; s > 0; s >>= 1) {
        if (tid < s) red[tid] += red[tid + s];
        __syncthreads();
    }
    if (tid < 128) {
        const float nrm = fmaxf(sqrtf(red[0]), 1e-12f);
        nproj[b * 128 + tid] = p / nrm;
    }
}

__global__ __launch_bounds__(256) void contrast_k(
    const float* __restrict__ nproj, const float* __restrict__ sums,
    float* __restrict__ out5)
{
    __shared__ float s_np[64 * 128];
    __shared__ float s_sim[64 * 64];
    __shared__ float s_row[64];
    const int tid = threadIdx.x;
    for (int i = tid; i < 64 * 128; i += 256) s_np[i] = nproj[i];
    __syncthreads();
    for (int p = tid; p < 64 * 64; p += 256) {
        const int i = p >> 6, j = p & 63;
        float d = 0.f;
        for (int k = 0; k < 128; ++k) d = fmaf(s_np[i * 128 + k], s_np[j * 128 + k], d);
        s_sim[p] = d * 10.f;
    }
    __syncthreads();
    if (tid < 64) {
        float mx = -1e30f;
        for (int j = 0; j < 64; ++j) mx = fmaxf(mx, s_sim[tid * 64 + j]);
        float se = 0.f;
        for (int j = 0; j < 64; ++j) se += expf(s_sim[tid * 64 + j] - mx);
        const float lse = mx + logf(se);
        s_row[tid] = s_sim[tid * 64 + tid] - lse;
    }
    __syncthreads();
    if (tid == 0) {
        float c = 0.f;
        for (int i = 0; i < 64; ++i) c += s_row[i];
        const float contr = -c / 64.f;
        const float recon = sums[0] / ((float)BT_TOK * (float)D_IN);
        const float commit = sums[1] / ((float)BT_TOK * (float)H2D);
        const float cbl = commit;
        const float total = recon * 1.0f + commit * 1.0f + cbl * 0.25f + contr * 0.5f;
        out5[0] = total;
        out5[1] = recon;
        out5[2] = commit;
        out5[3] = cbl;
        out5[4] = contr;
    }
}

__global__ void init_k(float* sums)
{
    if (threadIdx.x < 2) sums[threadIdx.x] = 0.f;
}

extern "C" void kernel_launch(void* const* d_in, const int* in_sizes, int n_in,
                              void* d_out, int out_size, void* d_ws, size_t ws_size,
                              hipStream_t stream)
{
    const float* x       = (const float*)d_in[0];
    const float* enc_w1  = (const float*)d_in[1];
    const float* enc_b1  = (const float*)d_in[2];
    const float* ln1_g   = (const float*)d_in[3];
    const float* ln1_b   = (const float*)d_in[4];
    const float* enc_w2  = (const float*)d_in[5];
    const float* enc_b2  = (const float*)d_in[6];
    const float* ln2_g   = (const float*)d_in[7];
    const float* ln2_b   = (const float*)d_in[8];
    const float* codebook= (const float*)d_in[9];
    const float* dec_w1  = (const float*)d_in[10];
    const float* dec_b1  = (const float*)d_in[11];
    const float* dec_w2  = (const float*)d_in[12];
    const float* dec_b2  = (const float*)d_in[13];
    const float* proj_w1 = (const float*)d_in[14];
    const float* proj_b1 = (const float*)d_in[15];
    const float* proj_w2 = (const float*)d_in[16];
    const float* proj_b2 = (const float*)d_in[17];
    float* out = (float*)d_out;

    char* wsb = (char*)d_ws;
    size_t off = 0;
    auto alloc = [&](size_t bytes) {
        void* p = wsb + off;
        off += (bytes + 255) & ~(size_t)255;
        return p;
    };

    f16* h1h  = (f16*)alloc((size_t)BT_TOK * H1D * 2);
    f16* h1l  = (f16*)alloc((size_t)BT_TOK * H1D * 2);
    f16* ench = (f16*)alloc((size_t)BT_TOK * H2D * 2);
    f16* encl = (f16*)alloc((size_t)BT_TOK * H2D * 2);
    f16* w1h  = (f16*)alloc((size_t)H1D * D_IN * 2);
    f16* w1l  = (f16*)alloc((size_t)H1D * D_IN * 2);
    f16* w2h  = (f16*)alloc((size_t)H2D * H1D * 2);
    f16* w2l  = (f16*)alloc((size_t)H2D * H1D * 2);
    f16* cbh  = (f16*)alloc((size_t)KCB * H2D * 2);
    f16* cbl  = (f16*)alloc((size_t)KCB * H2D * 2);
    unsigned short* cb_bf = (unsigned short*)alloc((size_t)KCB * H2D * 2);
    unsigned short* w1Td  = (unsigned short*)alloc((size_t)H1D * H2D * 2);
    unsigned short* w2Td  = (unsigned short*)alloc((size_t)D_IN * H1D * 2);
    float* cnorm  = (float*)alloc(KCB * 4);
    float* enorm  = (float*)alloc(BT_TOK * 4);
    float* cand_v = (float*)alloc((size_t)BT_TOK * 8 * 4);
    int*   cand_i = (int*)alloc((size_t)BT_TOK * 8 * 4);
    int*   idxbuf = (int*)alloc(BT_TOK * 4);
    float* pooled = (float*)alloc(64 * 512 * 4);
    float* nproj  = (float*)alloc(64 * 128 * 4);
    float* sums   = (float*)alloc(2 * 4);
    unsigned short* dh_bf = (unsigned short*)h1h;

    const dim3 blk(256);

    hipLaunchKernelGGL(init_k, dim3(1), blk, 0, stream, sums);

    splitT_k<<<dim3((H1D * D_IN + 255) / 256), blk, 0, stream>>>(enc_w1, w1h, w1l, D_IN, H1D);
    splitT_k<<<dim3((H2D * H1D + 255) / 256), blk, 0, stream>>>(enc_w2, w2h, w2l, H1D, H2D);
    split_k<<<dim3((KCB * H2D + 255) / 256), blk, 0, stream>>>(codebook, cbh, cbl, KCB * H2D);
    conv_k<<<dim3((KCB * H2D + 255) / 256), blk, 0, stream>>>(codebook, cb_bf, KCB * H2D);
    convT_k<<<dim3((H1D * H2D + 255) / 256), blk, 0, stream>>>(dec_w1, w1Td, H2D, H1D);
    convT_k<<<dim3((D_IN * H1D + 255) / 256), blk, 0, stream>>>(dec_w2, w2Td, H1D, D_IN);
    rowsumsq_k<<<dim3(KCB / 4), blk, 0, stream>>>(codebook, cnorm);

    // encoder layer 1 (split-fp16 MFMA, x split in-kernel): h1 = x @ enc_w1 + b1
    sgemm_k<0, true><<<dim3(H1D / 128, BT_TOK / 128), blk, 0, stream>>>(
        x, nullptr, nullptr, w1h, w1l, enc_b1, h1h, h1l, nullptr, nullptr, nullptr,
        H1D, D_IN);
    ln_pair_k<H1D, false><<<dim3(BT_TOK / 4), blk, 0, stream>>>(h1h, h1l, ln1_g, ln1_b, nullptr);

    // encoder layer 2: enc = h1 @ enc_w2 + b2
    sgemm_k<0, false><<<dim3(H2D / 128, BT_TOK / 128), blk, 0, stream>>>(
        nullptr, h1h, h1l, w2h, w2l, enc_b2, ench, encl, nullptr, nullptr, nullptr,
        H2D, H1D);
    ln_pair_k<H2D, true><<<dim3(BT_TOK / 4), blk, 0, stream>>>(ench, encl, ln2_g, ln2_b, enorm);

    // VQ scores + tile argmin
    sgemm_k<1, false><<<dim3(KCB / 128, BT_TOK / 128), blk, 0, stream>>>(
        nullptr, ench, encl, cbh, cbl, nullptr, nullptr, nullptr, cnorm, cand_v, cand_i,
        KCB, H2D);
    vq_reduce_k<<<dim3(BT_TOK / 256), blk, 0, stream>>>(
        cand_v, cand_i, enorm, out, idxbuf, sums + 1, 8);

    pooled_k<<<dim3(64), blk, 0, stream>>>(idxbuf, codebook, pooled);

    // decoder (bf16 MFMA)
    mfma_gemm_k<0><<<dim3(H1D / 128, BT_TOK / 128), blk, 0, stream>>>(
        cb_bf, w1Td, dec_b1, dh_bf, nullptr, nullptr, idxbuf, H1D, H2D);
    mfma_gemm_k<1><<<dim3(D_IN / 128, BT_TOK / 128), blk, 0, stream>>>(
        dh_bf, w2Td, dec_b2, nullptr, x, sums, nullptr, D_IN, H1D);

    proj_k<<<dim3(64), blk, 0, stream>>>(pooled, proj_w1, proj_b1, proj_w2, proj_b2, nproj);
    contrast_k<<<dim3(1), blk, 0, stream>>>(nproj, sums, out + BT_TOK);
}